// Round 20
// baseline (152.906 us; speedup 1.0000x reference)
//
#include <hip/hip_runtime.h>
#include <hip/hip_bf16.h>

#define NIMG 32
#define NPTS 300000
#define NL   64
#define NBOX 256

#define BANDS  4
#define BROWS  64          // NBOX / BANDS
#define CHUNKS 2
#define CHPTS  (NPTS / CHUNKS)   // 150000

#define WQS  2047.0f             // 11-bit weight quantization scale (16-bit field headroom)
#define WQI  (1.0f / 2047.0f)

typedef float v2f __attribute__((ext_vector_type(2)));
typedef float f32x4 __attribute__((ext_vector_type(4)));
typedef short bf16x8 __attribute__((ext_vector_type(8)));
typedef unsigned long long u64;

__device__ __forceinline__ int rev8(int x) { return (int)(__brev((unsigned)x) >> 24); }

// fp32 -> bf16 round-to-nearest-even
__device__ __forceinline__ short f2bf(float f) {
    unsigned u = __float_as_uint(f);
    unsigned r = (u + 0x7FFFu + ((u >> 16) & 1u)) >> 16;
    return (short)r;
}

// ---------------- zero fill ----------------
__global__ __launch_bounds__(256) void zero_kernel(float4* p, int n4) {
    int i = blockIdx.x * 256 + threadIdx.x;
    if (i < n4) p[i] = make_float4(0.f, 0.f, 0.f, 0.f);
}

// ---------------- P0: per-image fused coefficients + bf16 B matrix ----------------
// Bt[c][k] bf16, c = 2b -> u_b[k] (x-row of rotation applied to z), c = 2b+1 -> v_b[k]
// hdr[2b] = (R00,R01,R02, shx+128), hdr[2b+1] = (R10,R11,R12, shy+128)  (fp32)
__global__ __launch_bounds__(256) void uvprep_kernel(
    const float* __restrict__ z_x, const float* __restrict__ z_y,
    const float* __restrict__ z_z, const float* __restrict__ R,
    const float* __restrict__ shifts,
    float4* __restrict__ hdrbuf, short* __restrict__ Bt)
{
    __shared__ float s_u[NIMG * NL];   // 8 KB
    __shared__ float s_v[NIMG * NL];   // 8 KB
    int t = threadIdx.x;
    for (int e = t; e < NIMG * NL; e += 256) {
        int b = e >> 6;
        const float* Rb = R + b * 9;
        float zx = z_x[e], zy = z_y[e], zz = z_z[e];
        s_u[e] = Rb[0] * zx + Rb[1] * zy + Rb[2] * zz;
        s_v[e] = Rb[3] * zx + Rb[4] * zy + Rb[5] * zz;
    }
    if (t < NIMG) {
        const float* Rb = R + t * 9;
        hdrbuf[2 * t]     = make_float4(Rb[0], Rb[1], Rb[2], shifts[2 * t]     + 128.f);
        hdrbuf[2 * t + 1] = make_float4(Rb[3], Rb[4], Rb[5], shifts[2 * t + 1] + 128.f);
    }
    __syncthreads();
    for (int e = t; e < 64 * NL; e += 256) {
        int c = e >> 6, k = e & 63;
        int b = c >> 1;
        float val = (c & 1) ? s_v[b * NL + k] : s_u[b * NL + k];
        Bt[e] = f2bf(val);
    }
}

// ---------------- record packing (shared by both project variants) ----------------
__device__ __forceinline__ u64 make_rec(float px, float py, float w) {
    float x0f = floorf(px), y0f = floorf(py);
    float fx = px - x0f, fy = py - y0f;
    int xi0 = min(max((int)x0f, 0), NBOX - 1);
    int yi0 = min(max((int)y0f, 0), NBOX - 1);
    float w00 = w * (1.f - fx) * (1.f - fy);
    float w10 = w * fx * (1.f - fy);
    float w01 = w * (1.f - fx) * fy;
    float w11 = w * fx * fy;
    if (xi0 == NBOX - 1) {        // fold right column left
        w00 += w10; w10 = 0.f;
        w01 += w11; w11 = 0.f;
    }
    if (yi0 == NBOX - 1) {        // fold bottom row up
        w00 += w01; w01 = 0.f;
        w10 += w11; w11 = 0.f;
    }
    return (u64)(unsigned)(xi0 | (yi0 << 8))
         | ((u64)(unsigned)(w00 * WQS + 0.5f) << 16)
         | ((u64)(unsigned)(w10 * WQS + 0.5f) << 28)
         | ((u64)(unsigned)(w01 * WQS + 0.5f) << 40)
         | ((u64)(unsigned)(w11 * WQS + 0.5f) << 52);
}

// ---------------- P1: MFMA projection -> one u64 record per (image,point) ----------------
// GEMM: D[16 pts][64 cols] = Z_tile (16x64, bf16) x Bt^T; affine part added in fp32 epilogue.
// C/D layout (m89-verified): col = lane&15, row = (lane>>4)*4 + reg.
__global__ __launch_bounds__(256) void project_mfma_kernel(
    const float* __restrict__ Zb, const float* __restrict__ coords,
    const float* __restrict__ weights,
    const float4* __restrict__ hdrbuf, const short* __restrict__ Bt,
    u64* __restrict__ recs)
{
    int tid = threadIdx.x;
    int lane = tid & 63;
    int rg = (lane >> 4) & 3;
    bool oddl = (lane & 1);

    // B fragments, loaded once: bf[t][q] covers cols t*16..+15, k = q*32 + rg*8 .. +8
    bf16x8 bf[4][2];
    #pragma unroll
    for (int t = 0; t < 4; ++t)
        #pragma unroll
        for (int q = 0; q < 2; ++q)
            bf[t][q] = *(const bf16x8*)(Bt + (t * 16 + (lane & 15)) * NL + q * 32 + rg * 8);

    int wid = blockIdx.x * 4 + (tid >> 6);
    int nw  = gridDim.x * 4;
    for (int mt = wid; mt < NPTS / 16; mt += nw) {
        int pbase = mt * 16;
        // A fragments: row = lane&15, k = q*32 + rg*8 + j (same k convention as B)
        const float* zrow = Zb + (size_t)(pbase + (lane & 15)) * NL;
        bf16x8 a[2];
        #pragma unroll
        for (int q = 0; q < 2; ++q) {
            float4 f0 = *(const float4*)(zrow + q * 32 + rg * 8);
            float4 f1 = *(const float4*)(zrow + q * 32 + rg * 8 + 4);
            bf16x8 av;
            av[0] = f2bf(f0.x); av[1] = f2bf(f0.y); av[2] = f2bf(f0.z); av[3] = f2bf(f0.w);
            av[4] = f2bf(f1.x); av[5] = f2bf(f1.y); av[6] = f2bf(f1.z); av[7] = f2bf(f1.w);
            a[q] = av;
        }
        f32x4 accs[4];
        #pragma unroll
        for (int t = 0; t < 4; ++t) {
            f32x4 acc = {0.f, 0.f, 0.f, 0.f};
            acc = __builtin_amdgcn_mfma_f32_16x16x32_bf16(a[0], bf[t][0], acc, 0, 0, 0);
            acc = __builtin_amdgcn_mfma_f32_16x16x32_bf16(a[1], bf[t][1], acc, 0, 0, 0);
            accs[t] = acc;
        }

        // my two points: rows rg*4 + (oddl?2:0), +1
        int ra = rg * 4 + (oddl ? 2 : 0);
        int pa = pbase + ra;
        float cax = coords[3 * pa],     cay = coords[3 * pa + 1], caz = coords[3 * pa + 2];
        float cbx = coords[3 * pa + 3], cby = coords[3 * pa + 4], cbz = coords[3 * pa + 5];
        float wa = weights[pa], wb = weights[pa + 1];

        #pragma unroll
        for (int t = 0; t < 4; ++t) {
            f32x4 acc = accs[t];
            float o0 = __shfl_xor(acc[0], 1, 64);
            float o1 = __shfl_xor(acc[1], 1, 64);
            float o2 = __shfl_xor(acc[2], 1, 64);
            float o3 = __shfl_xor(acc[3], 1, 64);
            // my rows' components (static indexing via selects)
            float m0 = oddl ? acc[2] : acc[0];
            float m1 = oddl ? acc[3] : acc[1];
            float t0 = oddl ? o2 : o0;
            float t1 = oddl ? o3 : o1;
            // even lane holds x-col (dval_x), odd lane y-col
            float dxa = oddl ? t0 : m0;
            float dya = oddl ? m0 : t0;
            float dxb = oddl ? t1 : m1;
            float dyb = oddl ? m1 : t1;
            int col = t * 16 + (lane & 15);
            int img = col >> 1;
            float4 h0 = hdrbuf[2 * img], h1 = hdrbuf[2 * img + 1];
            float affxa = fmaf(h0.x, cax, fmaf(h0.y, cay, fmaf(h0.z, caz, h0.w)));
            float affya = fmaf(h1.x, cax, fmaf(h1.y, cay, fmaf(h1.z, caz, h1.w)));
            float affxb = fmaf(h0.x, cbx, fmaf(h0.y, cby, fmaf(h0.z, cbz, h0.w)));
            float affyb = fmaf(h1.x, cbx, fmaf(h1.y, cby, fmaf(h1.z, cbz, h1.w)));
            u64* pb = recs + (size_t)img * NPTS;
            pb[pa]     = make_rec(affxa + dxa, affya + dya, wa);
            pb[pa + 1] = make_rec(affxb + dxb, affyb + dyb, wb);
        }
    }
}

// ---------------- P2: band splat, ONE 2x2-quad u64 atomic per point-image ----------------
// BANDS=4, BROWS=64, quad views total 128.5 KB LDS, 1024-thread blocks (1 block/CU).
__global__ __launch_bounds__(1024) void splat2_kernel(
    const u64* __restrict__ recs, float* __restrict__ img)
{
    __shared__ u64 VA[32 * 128];   // 32 KB
    __shared__ u64 VB[32 * 129];   // 32.25 KB
    __shared__ u64 VC[32 * 128];   // 32 KB
    __shared__ u64 VD[32 * 129];   // 32.25 KB
    int tid = threadIdx.x;
    int id = blockIdx.x;           // band*64 + b*CHUNKS + c  (256 blocks)
    int band = id >> 6;            // 0..3
    int g    = id & 63;
    int b = g >> 1, c = g & 1;

    for (int i = tid; i < 32 * 128; i += 1024) { VA[i] = 0ULL; VC[i] = 0ULL; }
    for (int i = tid; i < 32 * 129; i += 1024) { VB[i] = 0ULL; VD[i] = 0ULL; }
    __syncthreads();

    const int y_lo = band * BROWS;
    const u64* rp = recs + (size_t)b * NPTS + (size_t)c * CHPTS;

    for (int i = 4 * tid; i < CHPTS; i += 4096) {
        ulonglong2 R01 = *(const ulonglong2*)(rp + i);       // points i, i+1
        ulonglong2 R23 = *(const ulonglong2*)(rp + i + 2);   // points i+2, i+3
        u64 Ra[4] = {R01.x, R01.y, R23.x, R23.y};
        #pragma unroll
        for (int k = 0; k < 4; ++k) {
            u64 rec = Ra[k];
            unsigned ps = (unsigned)rec & 0xFFFFu;
            int xi0 = ps & 255;
            int yi0 = ps >> 8;
            int r0 = yi0 - y_lo;
            if ((unsigned)r0 >= BROWS) continue;   // single ownership test
            u64 val = ((rec >> 16) & 0xFFFULL)
                    | (((rec >> 28) & 0xFFFULL) << 16)
                    | (((rec >> 40) & 0xFFFULL) << 32)
                    | (((rec >> 52) & 0xFFFULL) << 48);
            int qr = r0 >> 1;
            int qc = (xi0 + (xi0 & 1)) >> 1;
            bool xodd = (xi0 & 1), yodd = (r0 & 1);
            u64* base = yodd ? (xodd ? VD : VC) : (xodd ? VB : VA);
            int stride = xodd ? 129 : 128;
            atomicAdd(&base[qr * stride + qc], val);
        }
    }
    __syncthreads();
    // flush 65 rows (incl. halo row 64) with global atomic add
    int nrows = min(BROWS + 1, NBOX - y_lo);
    float* ib = img + (size_t)b * NBOX * NBOX + (size_t)y_lo * NBOX;
    for (int i = tid; i < nrows * NBOX; i += 1024) {
        int r = i >> 8, x = i & 255;
        int fc0 = x & 1;          // col field in VA/VC
        int fc1 = fc0 ^ 1;        // col field in VB/VD
        int ja = x >> 1;
        int jb = (x + 1) >> 1;
        unsigned acc = 0;
        if (r < BROWS) {
            int fr = (r & 1) << 1;
            acc += (unsigned)((VA[(r >> 1) * 128 + ja] >> (16 * (fr | fc0))) & 0xFFFFu);
            acc += (unsigned)((VB[(r >> 1) * 129 + jb] >> (16 * (fr | fc1))) & 0xFFFFu);
        }
        if (r >= 1) {
            int fr = ((r & 1) ^ 1) << 1;
            acc += (unsigned)((VC[((r - 1) >> 1) * 128 + ja] >> (16 * (fr | fc0))) & 0xFFFFu);
            acc += (unsigned)((VD[((r - 1) >> 1) * 129 + jb] >> (16 * (fr | fc1))) & 0xFFFFu);
        }
        if (acc) unsafeAtomicAdd(ib + i, (float)acc * WQI);
    }
}

// ---------------- fallback: fused splat with global atomics (small ws) ----------------
__global__ __launch_bounds__(256) void splat_kernel(
    const float* __restrict__ z_x, const float* __restrict__ z_y,
    const float* __restrict__ z_z, const float* __restrict__ Zb,
    const float* __restrict__ coords, const float* __restrict__ weights,
    const float* __restrict__ R, const float* __restrict__ shifts,
    float* __restrict__ img)
{
    __shared__ float s_z[3][NIMG][NL];
    __shared__ float s_R[NIMG][9];
    __shared__ float s_sh[NIMG][2];

    int tid = threadIdx.x;
    for (int i = tid; i < NIMG * NL; i += 256) {
        (&s_z[0][0][0])[i] = z_x[i];
        (&s_z[1][0][0])[i] = z_y[i];
        (&s_z[2][0][0])[i] = z_z[i];
    }
    for (int i = tid; i < NIMG * 9; i += 256) (&s_R[0][0])[i] = R[i];
    if (tid < NIMG * 2) (&s_sh[0][0])[tid] = shifts[tid];
    __syncthreads();

    int p = blockIdx.x * 256 + tid;
    if (p >= NPTS) return;

    float4 zr[16];
    const float4* Zr4 = (const float4*)(Zb + (size_t)p * NL);
    #pragma unroll
    for (int i = 0; i < 16; ++i) zr[i] = Zr4[i];

    float cx0 = coords[3 * p + 0];
    float cy0 = coords[3 * p + 1];
    float cz0 = coords[3 * p + 2];
    float w   = weights[p];

    for (int b = 0; b < NIMG; ++b) {
        const float4* zx4 = (const float4*)s_z[0][b];
        const float4* zy4 = (const float4*)s_z[1][b];
        const float4* zz4 = (const float4*)s_z[2][b];
        float dx = 0.f, dy = 0.f, dz = 0.f;
        #pragma unroll
        for (int i = 0; i < 16; ++i) {
            float4 a = zx4[i];
            dx += a.x * zr[i].x + a.y * zr[i].y + a.z * zr[i].z + a.w * zr[i].w;
            float4 bb = zy4[i];
            dy += bb.x * zr[i].x + bb.y * zr[i].y + bb.z * zr[i].z + bb.w * zr[i].w;
            float4 c = zz4[i];
            dz += c.x * zr[i].x + c.y * zr[i].y + c.z * zr[i].z + c.w * zr[i].w;
        }
        float cx = cx0 + dx, cy = cy0 + dy, cz = cz0 + dz;
        const float* Rb = s_R[b];
        float px = Rb[0] * cx + Rb[1] * cy + Rb[2] * cz + s_sh[b][0] + 128.0f;
        float py = Rb[3] * cx + Rb[4] * cy + Rb[5] * cz + s_sh[b][1] + 128.0f;

        float x0 = floorf(px), y0 = floorf(py);
        float fx = px - x0, fy = py - y0;
        int xi0 = min(max((int)x0, 0), NBOX - 1);
        int yi0 = min(max((int)y0, 0), NBOX - 1);
        int xi1 = min(xi0 + 1, NBOX - 1);
        int yi1 = min(yi0 + 1, NBOX - 1);

        float* ib = img + (size_t)b * NBOX * NBOX;
        unsafeAtomicAdd(ib + yi0 * NBOX + xi0, w * (1.f - fx) * (1.f - fy));
        unsafeAtomicAdd(ib + yi0 * NBOX + xi1, w * fx * (1.f - fy));
        unsafeAtomicAdd(ib + yi1 * NBOX + xi0, w * (1.f - fx) * fy);
        unsafeAtomicAdd(ib + yi1 * NBOX + xi1, w * fx * fy);
    }
}

// ---------------- 256-pt FFT helpers (AOS float2, LDS twiddle) ----------------
__device__ __forceinline__ void fft_dif_t(float2* s, const float2* tw, int t) {
    #pragma unroll
    for (int st = 7; st >= 0; --st) {
        int half = 1 << st;
        int j  = t & (half - 1);
        int i1 = ((t >> st) << (st + 1)) + j;
        int i2 = i1 + half;
        float2 a = s[i1], b = s[i2];
        float2 w = tw[j << (7 - st)];
        float dxr = a.x - b.x, dxi = a.y - b.y;
        s[i1] = make_float2(a.x + b.x, a.y + b.y);
        s[i2] = make_float2(w.x * dxr - w.y * dxi, w.x * dxi + w.y * dxr);
        __syncthreads();
    }
}

__device__ __forceinline__ void fft_dit_t(float2* s, const float2* tw, int t) {
    #pragma unroll
    for (int st = 0; st < 8; ++st) {
        int half = 1 << st;
        int j  = t & (half - 1);
        int i1 = ((t >> st) << (st + 1)) + j;
        int i2 = i1 + half;
        float2 a = s[i1], b = s[i2];
        float2 w = tw[j << (7 - st)];
        float cs = w.x, sn = -w.y;
        float tr = cs * b.x - sn * b.y;
        float ti = cs * b.y + sn * b.x;
        s[i1] = make_float2(a.x + tr, a.y + ti);
        s[i2] = make_float2(a.x - tr, a.y - ti);
        __syncthreads();
    }
}

// ---------------- SOA FFT helpers (8-col kernel) ----------------
__device__ __forceinline__ void fft_dif_soa(float* re, float* im, const float2* tw, int t) {
    #pragma unroll
    for (int st = 7; st >= 0; --st) {
        int half = 1 << st;
        int j  = t & (half - 1);
        int i1 = ((t >> st) << (st + 1)) + j;
        int i2 = i1 + half;
        float ar = re[i1], ai = im[i1], br = re[i2], bi = im[i2];
        float2 w = tw[j << (7 - st)];
        float dr = ar - br, di = ai - bi;
        re[i1] = ar + br;  im[i1] = ai + bi;
        re[i2] = w.x * dr - w.y * di;
        im[i2] = w.x * di + w.y * dr;
        __syncthreads();
    }
}

__device__ __forceinline__ void fft_dit_soa(float* re, float* im, const float2* tw, int t) {
    #pragma unroll
    for (int st = 0; st < 8; ++st) {
        int half = 1 << st;
        int j  = t & (half - 1);
        int i1 = ((t >> st) << (st + 1)) + j;
        int i2 = i1 + half;
        float ar = re[i1], ai = im[i1], br = re[i2], bi = im[i2];
        float2 w = tw[j << (7 - st)];
        float cs = w.x, sn = -w.y;
        float tr = cs * br - sn * bi;
        float ti = cs * bi + sn * br;
        re[i1] = ar + tr;  im[i1] = ai + ti;
        re[i2] = ar - tr;  im[i2] = ai - ti;
        __syncthreads();
    }
}

__device__ __forceinline__ void init_tw(float2* tw, int tid) {
    if (tid < 128) {
        float sn, cs;
        sincosf(-6.283185307179586f * (float)tid * (1.0f / 256.0f), &sn, &cs);
        tw[tid] = make_float2(cs, sn);
    }
}

// ---------------- Pass A: fused 5x5 blur + forward row FFT ----------------
__global__ __launch_bounds__(256) void fft_rows_fwd_blur_kernel(const float* __restrict__ img,
                                                                float2* __restrict__ freq)
{
    __shared__ float2 s[2][NBOX];
    __shared__ float  sb[2][NBOX];
    __shared__ float2 tw[128];
    int tid = threadIdx.x;
    int tx = tid & 127, ty = tid >> 7;
    init_tw(tw, tid);
    int row = blockIdx.x * 2 + ty;     // 0 .. B*N-1
    int b = row >> 8, y = row & (NBOX - 1);
    const float* ib = img + ((size_t)b << 16);
    const float gw[5] = {0.0544886845f, 0.2442013420f, 0.4026199469f,
                         0.2442013420f, 0.0544886845f};
    float acc0 = 0.f, acc1 = 0.f;
    #pragma unroll
    for (int dy = -2; dy <= 2; ++dy) {
        int yy = y + dy;
        if ((unsigned)yy < (unsigned)NBOX) {
            const float* rp = ib + yy * NBOX;
            acc0 += gw[dy + 2] * rp[tx];
            acc1 += gw[dy + 2] * rp[tx + 128];
        }
    }
    sb[ty][tx] = acc0;  sb[ty][tx + 128] = acc1;
    __syncthreads();
    float r0 = 0.f, r1 = 0.f;
    #pragma unroll
    for (int dx = -2; dx <= 2; ++dx) {
        int x0 = tx + dx, x1 = tx + 128 + dx;
        if ((unsigned)x0 < (unsigned)NBOX) r0 += gw[dx + 2] * sb[ty][x0];
        if ((unsigned)x1 < (unsigned)NBOX) r1 += gw[dx + 2] * sb[ty][x1];
    }
    s[ty][tx]       = make_float2(r0, 0.f);
    s[ty][tx + 128] = make_float2(r1, 0.f);
    __syncthreads();
    fft_dif_t(s[ty], tw, tx);
    float2* op = freq + (size_t)row * NBOX;
    op[tx]       = s[ty][tx];
    op[tx + 128] = s[ty][tx + 128];
}

// ---------------- Pass B: 8-column fused fwd-FFT * ctf * inv-FFT ----------------
__global__ __launch_bounds__(1024) void fft_cols_ctf8_kernel(float2* __restrict__ freq,
                                                             const float* __restrict__ ctf)
{
    __shared__ float  s_re[8][257];
    __shared__ float  s_im[8][257];
    __shared__ float2 tw[128];
    int tid = threadIdx.x;
    init_tw(tw, tid);
    int col = tid & 7, j = tid >> 3;          // j in 0..127
    int blk = blockIdx.x;
    int b = blk >> 5;
    int x = ((blk & 31) << 3) + col;          // storage x
    float2* base = freq + ((size_t)b << 16) + x;

    float2 v0 = base[(size_t)j * NBOX];
    float2 v1 = base[(size_t)(j + 128) * NBOX];
    s_re[col][j] = v0.x;        s_im[col][j] = v0.y;
    s_re[col][j + 128] = v1.x;  s_im[col][j + 128] = v1.y;
    __syncthreads();

    fft_dif_soa(s_re[col], s_im[col], tw, j);

    const float* cb = ctf + ((size_t)b << 16) + rev8(x);
    float c0 = cb[rev8(j) * NBOX];
    float c1 = cb[rev8(j + 128) * NBOX];
    s_re[col][j] *= c0;        s_im[col][j] *= c0;
    s_re[col][j + 128] *= c1;  s_im[col][j + 128] *= c1;
    __syncthreads();

    fft_dit_soa(s_re[col], s_im[col], tw, j);

    const float inv = 1.0f / 256.0f;
    base[(size_t)j * NBOX]         = make_float2(s_re[col][j] * inv, s_im[col][j] * inv);
    base[(size_t)(j + 128) * NBOX] = make_float2(s_re[col][j + 128] * inv, s_im[col][j + 128] * inv);
}

// ---------------- Pass C: inverse row FFT -> real output ----------------
__global__ __launch_bounds__(256) void fft_rows_inv_kernel(const float2* __restrict__ freq,
                                                           float* __restrict__ out)
{
    __shared__ float2 s[2][NBOX];
    __shared__ float2 tw[128];
    int tid = threadIdx.x;
    int tx = tid & 127, ty = tid >> 7;
    init_tw(tw, tid);
    int row = blockIdx.x * 2 + ty;
    const float2* rp = freq + (size_t)row * NBOX;
    s[ty][tx]       = rp[tx];
    s[ty][tx + 128] = rp[tx + 128];
    __syncthreads();
    fft_dit_t(s[ty], tw, tx);
    const float inv = 1.0f / 256.0f;
    out[(size_t)row * NBOX + tx]       = s[ty][tx].x * inv;
    out[(size_t)row * NBOX + tx + 128] = s[ty][tx + 128].x * inv;
}

extern "C" void kernel_launch(void* const* d_in, const int* in_sizes, int n_in,
                              void* d_out, int out_size, void* d_ws, size_t ws_size,
                              hipStream_t stream)
{
    (void)in_sizes; (void)n_in; (void)out_size;
    const float* z_x     = (const float*)d_in[0];
    const float* z_y     = (const float*)d_in[1];
    const float* z_z     = (const float*)d_in[2];
    const float* Zb      = (const float*)d_in[3];
    const float* coords  = (const float*)d_in[4];
    const float* weights = (const float*)d_in[5];
    const float* R       = (const float*)d_in[6];
    const float* shifts  = (const float*)d_in[7];
    const float* ctf     = (const float*)d_in[8];
    float* out = (float*)d_out;

    const size_t NELEM = (size_t)NIMG * NBOX * NBOX;           // 2,097,152
    char* base = (char*)d_ws;
    float* img  = (float*)base;                                 // 8 MB
    u64*   recs = (u64*)(base + 8388608);                       // 76.8 MB
    float4* hdrbuf = (float4*)(base + 8388608 + 76800000);      // 1 KB
    short*  Bt     = (short*)(base + 8388608 + 76800000 + 1024);// 8 KB
    // freq aliases recs (recs dead after splat2; freq written after)
    float2* freq = (float2*)(base + 8388608);                   // 16.78 MB < 76.8 MB
    const size_t required = 8388608 + 76800000 + 1024 + 8192;

    zero_kernel<<<(int)(NELEM / 4 + 255) / 256, 256, 0, stream>>>((float4*)img, (int)(NELEM / 4));

    if (ws_size >= required) {
        uvprep_kernel<<<1, 256, 0, stream>>>(z_x, z_y, z_z, R, shifts, hdrbuf, Bt);
        project_mfma_kernel<<<2048, 256, 0, stream>>>(Zb, coords, weights,
                                                      hdrbuf, Bt, recs);
        splat2_kernel<<<NIMG * BANDS * CHUNKS, 1024, 0, stream>>>(recs, img);
    } else {
        splat_kernel<<<(NPTS + 255) / 256, 256, 0, stream>>>(z_x, z_y, z_z, Zb, coords,
                                                             weights, R, shifts, img);
    }

    // fused blur + row FFT
    fft_rows_fwd_blur_kernel<<<NIMG * NBOX / 2, 256, 0, stream>>>(img, freq);
    // 8-column fused col-FFT * ctf * inv-col-FFT
    fft_cols_ctf8_kernel<<<NIMG * 32, 1024, 0, stream>>>(freq, ctf);
    // inverse row FFT -> real out
    fft_rows_inv_kernel<<<NIMG * NBOX / 2, 256, 0, stream>>>(freq, out);
}

// Round 21
// 140.139 us; speedup vs baseline: 1.0911x; 1.0911x over previous
//
#include <hip/hip_runtime.h>
#include <hip/hip_bf16.h>

#define NIMG 32
#define NPTS 300000
#define NL   64
#define NBOX 256

#define BANDS  4
#define BROWS  64          // NBOX / BANDS
#define CHUNKS 2
#define CHPTS  (NPTS / CHUNKS)   // 150000

#define WQS  2047.0f             // 11-bit weight quantization scale (16-bit field headroom)
#define WQI  (1.0f / 2047.0f)

typedef float v2f __attribute__((ext_vector_type(2)));
typedef float f32x4 __attribute__((ext_vector_type(4)));
typedef short bf16x8 __attribute__((ext_vector_type(8)));
typedef unsigned long long u64;

__device__ __forceinline__ int rev8(int x) { return (int)(__brev((unsigned)x) >> 24); }

// fp32 -> bf16 round-to-nearest-even
__device__ __forceinline__ short f2bf(float f) {
    unsigned u = __float_as_uint(f);
    unsigned r = (u + 0x7FFFu + ((u >> 16) & 1u)) >> 16;
    return (short)r;
}

// ---------------- zero fill ----------------
__global__ __launch_bounds__(256) void zero_kernel(float4* p, int n4) {
    int i = blockIdx.x * 256 + threadIdx.x;
    if (i < n4) p[i] = make_float4(0.f, 0.f, 0.f, 0.f);
}

// ---------------- P0: per-image fused coefficients + bf16 B matrix ----------------
__global__ __launch_bounds__(256) void uvprep_kernel(
    const float* __restrict__ z_x, const float* __restrict__ z_y,
    const float* __restrict__ z_z, const float* __restrict__ R,
    const float* __restrict__ shifts,
    float4* __restrict__ hdrbuf, short* __restrict__ Bt)
{
    __shared__ float s_u[NIMG * NL];   // 8 KB
    __shared__ float s_v[NIMG * NL];   // 8 KB
    int t = threadIdx.x;
    for (int e = t; e < NIMG * NL; e += 256) {
        int b = e >> 6;
        const float* Rb = R + b * 9;
        float zx = z_x[e], zy = z_y[e], zz = z_z[e];
        s_u[e] = Rb[0] * zx + Rb[1] * zy + Rb[2] * zz;
        s_v[e] = Rb[3] * zx + Rb[4] * zy + Rb[5] * zz;
    }
    if (t < NIMG) {
        const float* Rb = R + t * 9;
        hdrbuf[2 * t]     = make_float4(Rb[0], Rb[1], Rb[2], shifts[2 * t]     + 128.f);
        hdrbuf[2 * t + 1] = make_float4(Rb[3], Rb[4], Rb[5], shifts[2 * t + 1] + 128.f);
    }
    __syncthreads();
    for (int e = t; e < 64 * NL; e += 256) {
        int c = e >> 6, k = e & 63;
        int b = c >> 1;
        float val = (c & 1) ? s_v[b * NL + k] : s_u[b * NL + k];
        Bt[e] = f2bf(val);
    }
}

// ---------------- record packing ----------------
__device__ __forceinline__ u64 make_rec(float px, float py, float w) {
    float x0f = floorf(px), y0f = floorf(py);
    float fx = px - x0f, fy = py - y0f;
    int xi0 = min(max((int)x0f, 0), NBOX - 1);
    int yi0 = min(max((int)y0f, 0), NBOX - 1);
    float w00 = w * (1.f - fx) * (1.f - fy);
    float w10 = w * fx * (1.f - fy);
    float w01 = w * (1.f - fx) * fy;
    float w11 = w * fx * fy;
    if (xi0 == NBOX - 1) {        // fold right column left
        w00 += w10; w10 = 0.f;
        w01 += w11; w11 = 0.f;
    }
    if (yi0 == NBOX - 1) {        // fold bottom row up
        w00 += w01; w01 = 0.f;
        w10 += w11; w11 = 0.f;
    }
    return (u64)(unsigned)(xi0 | (yi0 << 8))
         | ((u64)(unsigned)(w00 * WQS + 0.5f) << 16)
         | ((u64)(unsigned)(w10 * WQS + 0.5f) << 28)
         | ((u64)(unsigned)(w01 * WQS + 0.5f) << 40)
         | ((u64)(unsigned)(w11 * WQS + 0.5f) << 52);
}

// ---------------- P1: MFMA projection -> one u64 record per (image,point) ----------------
__global__ __launch_bounds__(256) void project_mfma_kernel(
    const float* __restrict__ Zb, const float* __restrict__ coords,
    const float* __restrict__ weights,
    const float4* __restrict__ hdrbuf, const short* __restrict__ Bt,
    u64* __restrict__ recs)
{
    int tid = threadIdx.x;
    int lane = tid & 63;
    int rg = (lane >> 4) & 3;
    bool oddl = (lane & 1);

    bf16x8 bf[4][2];
    #pragma unroll
    for (int t = 0; t < 4; ++t)
        #pragma unroll
        for (int q = 0; q < 2; ++q)
            bf[t][q] = *(const bf16x8*)(Bt + (t * 16 + (lane & 15)) * NL + q * 32 + rg * 8);

    int wid = blockIdx.x * 4 + (tid >> 6);
    int nw  = gridDim.x * 4;
    for (int mt = wid; mt < NPTS / 16; mt += nw) {
        int pbase = mt * 16;
        const float* zrow = Zb + (size_t)(pbase + (lane & 15)) * NL;
        bf16x8 a[2];
        #pragma unroll
        for (int q = 0; q < 2; ++q) {
            float4 f0 = *(const float4*)(zrow + q * 32 + rg * 8);
            float4 f1 = *(const float4*)(zrow + q * 32 + rg * 8 + 4);
            bf16x8 av;
            av[0] = f2bf(f0.x); av[1] = f2bf(f0.y); av[2] = f2bf(f0.z); av[3] = f2bf(f0.w);
            av[4] = f2bf(f1.x); av[5] = f2bf(f1.y); av[6] = f2bf(f1.z); av[7] = f2bf(f1.w);
            a[q] = av;
        }
        f32x4 accs[4];
        #pragma unroll
        for (int t = 0; t < 4; ++t) {
            f32x4 acc = {0.f, 0.f, 0.f, 0.f};
            acc = __builtin_amdgcn_mfma_f32_16x16x32_bf16(a[0], bf[t][0], acc, 0, 0, 0);
            acc = __builtin_amdgcn_mfma_f32_16x16x32_bf16(a[1], bf[t][1], acc, 0, 0, 0);
            accs[t] = acc;
        }

        int ra = rg * 4 + (oddl ? 2 : 0);
        int pa = pbase + ra;
        float cax = coords[3 * pa],     cay = coords[3 * pa + 1], caz = coords[3 * pa + 2];
        float cbx = coords[3 * pa + 3], cby = coords[3 * pa + 4], cbz = coords[3 * pa + 5];
        float wa = weights[pa], wb = weights[pa + 1];

        #pragma unroll
        for (int t = 0; t < 4; ++t) {
            f32x4 acc = accs[t];
            float o0 = __shfl_xor(acc[0], 1, 64);
            float o1 = __shfl_xor(acc[1], 1, 64);
            float o2 = __shfl_xor(acc[2], 1, 64);
            float o3 = __shfl_xor(acc[3], 1, 64);
            float m0 = oddl ? acc[2] : acc[0];
            float m1 = oddl ? acc[3] : acc[1];
            float t0 = oddl ? o2 : o0;
            float t1 = oddl ? o3 : o1;
            float dxa = oddl ? t0 : m0;
            float dya = oddl ? m0 : t0;
            float dxb = oddl ? t1 : m1;
            float dyb = oddl ? m1 : t1;
            int col = t * 16 + (lane & 15);
            int img = col >> 1;
            float4 h0 = hdrbuf[2 * img], h1 = hdrbuf[2 * img + 1];
            float affxa = fmaf(h0.x, cax, fmaf(h0.y, cay, fmaf(h0.z, caz, h0.w)));
            float affya = fmaf(h1.x, cax, fmaf(h1.y, cay, fmaf(h1.z, caz, h1.w)));
            float affxb = fmaf(h0.x, cbx, fmaf(h0.y, cby, fmaf(h0.z, cbz, h0.w)));
            float affyb = fmaf(h1.x, cbx, fmaf(h1.y, cby, fmaf(h1.z, cbz, h1.w)));
            u64* pb = recs + (size_t)img * NPTS;
            pb[pa]     = make_rec(affxa + dxa, affya + dya, wa);
            pb[pa + 1] = make_rec(affxb + dxb, affyb + dyb, wb);
        }
    }
}

// ---------------- P2: band splat, ONE 2x2-quad u64 atomic per point-image ----------------
__global__ __launch_bounds__(1024) void splat2_kernel(
    const u64* __restrict__ recs, float* __restrict__ img)
{
    __shared__ u64 VA[32 * 128];   // 32 KB
    __shared__ u64 VB[32 * 129];   // 32.25 KB
    __shared__ u64 VC[32 * 128];   // 32 KB
    __shared__ u64 VD[32 * 129];   // 32.25 KB
    int tid = threadIdx.x;
    int id = blockIdx.x;           // band*64 + b*CHUNKS + c  (256 blocks)
    int band = id >> 6;            // 0..3
    int g    = id & 63;
    int b = g >> 1, c = g & 1;

    for (int i = tid; i < 32 * 128; i += 1024) { VA[i] = 0ULL; VC[i] = 0ULL; }
    for (int i = tid; i < 32 * 129; i += 1024) { VB[i] = 0ULL; VD[i] = 0ULL; }
    __syncthreads();

    const int y_lo = band * BROWS;
    const u64* rp = recs + (size_t)b * NPTS + (size_t)c * CHPTS;

    for (int i = 4 * tid; i < CHPTS; i += 4096) {
        ulonglong2 R01 = *(const ulonglong2*)(rp + i);
        ulonglong2 R23 = *(const ulonglong2*)(rp + i + 2);
        u64 Ra[4] = {R01.x, R01.y, R23.x, R23.y};
        #pragma unroll
        for (int k = 0; k < 4; ++k) {
            u64 rec = Ra[k];
            unsigned ps = (unsigned)rec & 0xFFFFu;
            int xi0 = ps & 255;
            int yi0 = ps >> 8;
            int r0 = yi0 - y_lo;
            if ((unsigned)r0 >= BROWS) continue;
            u64 val = ((rec >> 16) & 0xFFFULL)
                    | (((rec >> 28) & 0xFFFULL) << 16)
                    | (((rec >> 40) & 0xFFFULL) << 32)
                    | (((rec >> 52) & 0xFFFULL) << 48);
            int qr = r0 >> 1;
            int qc = (xi0 + (xi0 & 1)) >> 1;
            bool xodd = (xi0 & 1), yodd = (r0 & 1);
            u64* base = yodd ? (xodd ? VD : VC) : (xodd ? VB : VA);
            int stride = xodd ? 129 : 128;
            atomicAdd(&base[qr * stride + qc], val);
        }
    }
    __syncthreads();
    int nrows = min(BROWS + 1, NBOX - y_lo);
    float* ib = img + (size_t)b * NBOX * NBOX + (size_t)y_lo * NBOX;
    for (int i = tid; i < nrows * NBOX; i += 1024) {
        int r = i >> 8, x = i & 255;
        int fc0 = x & 1;
        int fc1 = fc0 ^ 1;
        int ja = x >> 1;
        int jb = (x + 1) >> 1;
        unsigned acc = 0;
        if (r < BROWS) {
            int fr = (r & 1) << 1;
            acc += (unsigned)((VA[(r >> 1) * 128 + ja] >> (16 * (fr | fc0))) & 0xFFFFu);
            acc += (unsigned)((VB[(r >> 1) * 129 + jb] >> (16 * (fr | fc1))) & 0xFFFFu);
        }
        if (r >= 1) {
            int fr = ((r & 1) ^ 1) << 1;
            acc += (unsigned)((VC[((r - 1) >> 1) * 128 + ja] >> (16 * (fr | fc0))) & 0xFFFFu);
            acc += (unsigned)((VD[((r - 1) >> 1) * 129 + jb] >> (16 * (fr | fc1))) & 0xFFFFu);
        }
        if (acc) unsafeAtomicAdd(ib + i, (float)acc * WQI);
    }
}

// ---------------- fallback: fused splat with global atomics (small ws) ----------------
__global__ __launch_bounds__(256) void splat_kernel(
    const float* __restrict__ z_x, const float* __restrict__ z_y,
    const float* __restrict__ z_z, const float* __restrict__ Zb,
    const float* __restrict__ coords, const float* __restrict__ weights,
    const float* __restrict__ R, const float* __restrict__ shifts,
    float* __restrict__ img)
{
    __shared__ float s_z[3][NIMG][NL];
    __shared__ float s_R[NIMG][9];
    __shared__ float s_sh[NIMG][2];

    int tid = threadIdx.x;
    for (int i = tid; i < NIMG * NL; i += 256) {
        (&s_z[0][0][0])[i] = z_x[i];
        (&s_z[1][0][0])[i] = z_y[i];
        (&s_z[2][0][0])[i] = z_z[i];
    }
    for (int i = tid; i < NIMG * 9; i += 256) (&s_R[0][0])[i] = R[i];
    if (tid < NIMG * 2) (&s_sh[0][0])[tid] = shifts[tid];
    __syncthreads();

    int p = blockIdx.x * 256 + tid;
    if (p >= NPTS) return;

    float4 zr[16];
    const float4* Zr4 = (const float4*)(Zb + (size_t)p * NL);
    #pragma unroll
    for (int i = 0; i < 16; ++i) zr[i] = Zr4[i];

    float cx0 = coords[3 * p + 0];
    float cy0 = coords[3 * p + 1];
    float cz0 = coords[3 * p + 2];
    float w   = weights[p];

    for (int b = 0; b < NIMG; ++b) {
        const float4* zx4 = (const float4*)s_z[0][b];
        const float4* zy4 = (const float4*)s_z[1][b];
        const float4* zz4 = (const float4*)s_z[2][b];
        float dx = 0.f, dy = 0.f, dz = 0.f;
        #pragma unroll
        for (int i = 0; i < 16; ++i) {
            float4 a = zx4[i];
            dx += a.x * zr[i].x + a.y * zr[i].y + a.z * zr[i].z + a.w * zr[i].w;
            float4 bb = zy4[i];
            dy += bb.x * zr[i].x + bb.y * zr[i].y + bb.z * zr[i].z + bb.w * zr[i].w;
            float4 c = zz4[i];
            dz += c.x * zr[i].x + c.y * zr[i].y + c.z * zr[i].z + c.w * zr[i].w;
        }
        float cx = cx0 + dx, cy = cy0 + dy, cz = cz0 + dz;
        const float* Rb = s_R[b];
        float px = Rb[0] * cx + Rb[1] * cy + Rb[2] * cz + s_sh[b][0] + 128.0f;
        float py = Rb[3] * cx + Rb[4] * cy + Rb[5] * cz + s_sh[b][1] + 128.0f;

        float x0 = floorf(px), y0 = floorf(py);
        float fx = px - x0, fy = py - y0;
        int xi0 = min(max((int)x0, 0), NBOX - 1);
        int yi0 = min(max((int)y0, 0), NBOX - 1);
        int xi1 = min(xi0 + 1, NBOX - 1);
        int yi1 = min(yi0 + 1, NBOX - 1);

        float* ib = img + (size_t)b * NBOX * NBOX;
        unsafeAtomicAdd(ib + yi0 * NBOX + xi0, w * (1.f - fx) * (1.f - fy));
        unsafeAtomicAdd(ib + yi0 * NBOX + xi1, w * fx * (1.f - fy));
        unsafeAtomicAdd(ib + yi1 * NBOX + xi0, w * (1.f - fx) * fy);
        unsafeAtomicAdd(ib + yi1 * NBOX + xi1, w * fx * fy);
    }
}

// ---------------- 256-pt FFT helpers (AOS float2, LDS twiddle) ----------------
__device__ __forceinline__ void fft_dif_t(float2* s, const float2* tw, int t) {
    #pragma unroll
    for (int st = 7; st >= 0; --st) {
        int half = 1 << st;
        int j  = t & (half - 1);
        int i1 = ((t >> st) << (st + 1)) + j;
        int i2 = i1 + half;
        float2 a = s[i1], b = s[i2];
        float2 w = tw[j << (7 - st)];
        float dxr = a.x - b.x, dxi = a.y - b.y;
        s[i1] = make_float2(a.x + b.x, a.y + b.y);
        s[i2] = make_float2(w.x * dxr - w.y * dxi, w.x * dxi + w.y * dxr);
        __syncthreads();
    }
}

__device__ __forceinline__ void fft_dit_t(float2* s, const float2* tw, int t) {
    #pragma unroll
    for (int st = 0; st < 8; ++st) {
        int half = 1 << st;
        int j  = t & (half - 1);
        int i1 = ((t >> st) << (st + 1)) + j;
        int i2 = i1 + half;
        float2 a = s[i1], b = s[i2];
        float2 w = tw[j << (7 - st)];
        float cs = w.x, sn = -w.y;
        float tr = cs * b.x - sn * b.y;
        float ti = cs * b.y + sn * b.x;
        s[i1] = make_float2(a.x + tr, a.y + ti);
        s[i2] = make_float2(a.x - tr, a.y - ti);
        __syncthreads();
    }
}

__device__ __forceinline__ void init_tw(float2* tw, int tid) {
    if (tid < 128) {
        float sn, cs;
        sincosf(-6.283185307179586f * (float)tid * (1.0f / 256.0f), &sn, &cs);
        tw[tid] = make_float2(cs, sn);
    }
}

// ---------------- Pass A: fused 5x5 blur + forward row FFT ----------------
__global__ __launch_bounds__(256) void fft_rows_fwd_blur_kernel(const float* __restrict__ img,
                                                                float2* __restrict__ freq)
{
    __shared__ float2 s[2][NBOX];
    __shared__ float  sb[2][NBOX];
    __shared__ float2 tw[128];
    int tid = threadIdx.x;
    int tx = tid & 127, ty = tid >> 7;
    init_tw(tw, tid);
    int row = blockIdx.x * 2 + ty;     // 0 .. B*N-1
    int b = row >> 8, y = row & (NBOX - 1);
    const float* ib = img + ((size_t)b << 16);
    const float gw[5] = {0.0544886845f, 0.2442013420f, 0.4026199469f,
                         0.2442013420f, 0.0544886845f};
    float acc0 = 0.f, acc1 = 0.f;
    #pragma unroll
    for (int dy = -2; dy <= 2; ++dy) {
        int yy = y + dy;
        if ((unsigned)yy < (unsigned)NBOX) {
            const float* rp = ib + yy * NBOX;
            acc0 += gw[dy + 2] * rp[tx];
            acc1 += gw[dy + 2] * rp[tx + 128];
        }
    }
    sb[ty][tx] = acc0;  sb[ty][tx + 128] = acc1;
    __syncthreads();
    float r0 = 0.f, r1 = 0.f;
    #pragma unroll
    for (int dx = -2; dx <= 2; ++dx) {
        int x0 = tx + dx, x1 = tx + 128 + dx;
        if ((unsigned)x0 < (unsigned)NBOX) r0 += gw[dx + 2] * sb[ty][x0];
        if ((unsigned)x1 < (unsigned)NBOX) r1 += gw[dx + 2] * sb[ty][x1];
    }
    s[ty][tx]       = make_float2(r0, 0.f);
    s[ty][tx + 128] = make_float2(r1, 0.f);
    __syncthreads();
    fft_dif_t(s[ty], tw, tx);
    float2* op = freq + (size_t)row * NBOX;
    op[tx]       = s[ty][tx];
    op[tx + 128] = s[ty][tx + 128];
}

// ---------------- Pass B: 32-column fused fwd-FFT * ctf * inv-FFT (coalesced) ----------------
// col = tid&31 (32 cols/block), tq = tid>>5; loads/stores 256B-contiguous per row.
// LDS stride 257 -> bank (col+i)&31, conflict-free across the 32 cols of a half-wave.
__global__ __launch_bounds__(1024) void fft_cols_ctf32_kernel(float2* __restrict__ freq,
                                                              const float* __restrict__ ctf)
{
    __shared__ float  s_re[32][257];   // 32.9 KB
    __shared__ float  s_im[32][257];   // 32.9 KB
    __shared__ float2 tw[128];
    int tid = threadIdx.x;
    init_tw(tw, tid);
    int col = tid & 31, tq = tid >> 5;        // tq in 0..31
    int blk = blockIdx.x;
    int b = blk >> 3;
    int x = ((blk & 7) << 5) + col;           // storage x
    float2* base = freq + ((size_t)b << 16) + x;

    #pragma unroll
    for (int k = 0; k < 8; ++k) {
        int j = tq + 32 * k;
        float2 v = base[(size_t)j * NBOX];
        s_re[col][j] = v.x;  s_im[col][j] = v.y;
    }
    __syncthreads();

    // DIF forward: t = tq + 32k, k=0..3 (disjoint butterfly pairs within a stage)
    #pragma unroll
    for (int st = 7; st >= 0; --st) {
        int half = 1 << st;
        #pragma unroll
        for (int k = 0; k < 4; ++k) {
            int t = tq + 32 * k;
            int jj = t & (half - 1);
            int i1 = ((t >> st) << (st + 1)) + jj;
            int i2 = i1 + half;
            float ar = s_re[col][i1], ai = s_im[col][i1];
            float br = s_re[col][i2], bi = s_im[col][i2];
            float2 w = tw[jj << (7 - st)];
            float dr = ar - br, di = ai - bi;
            s_re[col][i1] = ar + br;  s_im[col][i1] = ai + bi;
            s_re[col][i2] = w.x * dr - w.y * di;
            s_im[col][i2] = w.x * di + w.y * dr;
        }
        __syncthreads();
    }

    // ctf multiply: element j holds y-freq rev8(j); this column holds x-freq rev8(x)
    const float* cb = ctf + ((size_t)b << 16) + rev8(x);
    #pragma unroll
    for (int k = 0; k < 8; ++k) {
        int j = tq + 32 * k;
        float c = cb[rev8(j) * NBOX];
        s_re[col][j] *= c;  s_im[col][j] *= c;
    }
    __syncthreads();

    // DIT inverse
    #pragma unroll
    for (int st = 0; st < 8; ++st) {
        int half = 1 << st;
        #pragma unroll
        for (int k = 0; k < 4; ++k) {
            int t = tq + 32 * k;
            int jj = t & (half - 1);
            int i1 = ((t >> st) << (st + 1)) + jj;
            int i2 = i1 + half;
            float ar = s_re[col][i1], ai = s_im[col][i1];
            float br = s_re[col][i2], bi = s_im[col][i2];
            float2 w = tw[jj << (7 - st)];
            float cs = w.x, sn = -w.y;
            float tr = cs * br - sn * bi;
            float ti = cs * bi + sn * br;
            s_re[col][i1] = ar + tr;  s_im[col][i1] = ai + ti;
            s_re[col][i2] = ar - tr;  s_im[col][i2] = ai - ti;
        }
        __syncthreads();
    }

    const float inv = 1.0f / 256.0f;
    #pragma unroll
    for (int k = 0; k < 8; ++k) {
        int j = tq + 32 * k;
        base[(size_t)j * NBOX] = make_float2(s_re[col][j] * inv, s_im[col][j] * inv);
    }
}

// ---------------- Pass C: inverse row FFT -> real output ----------------
__global__ __launch_bounds__(256) void fft_rows_inv_kernel(const float2* __restrict__ freq,
                                                           float* __restrict__ out)
{
    __shared__ float2 s[2][NBOX];
    __shared__ float2 tw[128];
    int tid = threadIdx.x;
    int tx = tid & 127, ty = tid >> 7;
    init_tw(tw, tid);
    int row = blockIdx.x * 2 + ty;
    const float2* rp = freq + (size_t)row * NBOX;
    s[ty][tx]       = rp[tx];
    s[ty][tx + 128] = rp[tx + 128];
    __syncthreads();
    fft_dit_t(s[ty], tw, tx);
    const float inv = 1.0f / 256.0f;
    out[(size_t)row * NBOX + tx]       = s[ty][tx].x * inv;
    out[(size_t)row * NBOX + tx + 128] = s[ty][tx + 128].x * inv;
}

extern "C" void kernel_launch(void* const* d_in, const int* in_sizes, int n_in,
                              void* d_out, int out_size, void* d_ws, size_t ws_size,
                              hipStream_t stream)
{
    (void)in_sizes; (void)n_in; (void)out_size;
    const float* z_x     = (const float*)d_in[0];
    const float* z_y     = (const float*)d_in[1];
    const float* z_z     = (const float*)d_in[2];
    const float* Zb      = (const float*)d_in[3];
    const float* coords  = (const float*)d_in[4];
    const float* weights = (const float*)d_in[5];
    const float* R       = (const float*)d_in[6];
    const float* shifts  = (const float*)d_in[7];
    const float* ctf     = (const float*)d_in[8];
    float* out = (float*)d_out;

    const size_t NELEM = (size_t)NIMG * NBOX * NBOX;           // 2,097,152
    char* base = (char*)d_ws;
    float* img  = (float*)base;                                 // 8 MB
    u64*   recs = (u64*)(base + 8388608);                       // 76.8 MB
    float4* hdrbuf = (float4*)(base + 8388608 + 76800000);      // 1 KB
    short*  Bt     = (short*)(base + 8388608 + 76800000 + 1024);// 8 KB
    // freq aliases recs (recs dead after splat2; freq written after)
    float2* freq = (float2*)(base + 8388608);                   // 16.78 MB < 76.8 MB
    const size_t required = 8388608 + 76800000 + 1024 + 8192;

    zero_kernel<<<(int)(NELEM / 4 + 255) / 256, 256, 0, stream>>>((float4*)img, (int)(NELEM / 4));

    if (ws_size >= required) {
        uvprep_kernel<<<1, 256, 0, stream>>>(z_x, z_y, z_z, R, shifts, hdrbuf, Bt);
        project_mfma_kernel<<<2048, 256, 0, stream>>>(Zb, coords, weights,
                                                      hdrbuf, Bt, recs);
        splat2_kernel<<<NIMG * BANDS * CHUNKS, 1024, 0, stream>>>(recs, img);
    } else {
        splat_kernel<<<(NPTS + 255) / 256, 256, 0, stream>>>(z_x, z_y, z_z, Zb, coords,
                                                             weights, R, shifts, img);
    }

    // fused blur + row FFT
    fft_rows_fwd_blur_kernel<<<NIMG * NBOX / 2, 256, 0, stream>>>(img, freq);
    // 32-column fused col-FFT * ctf * inv-col-FFT (coalesced)
    fft_cols_ctf32_kernel<<<NIMG * 8, 1024, 0, stream>>>(freq, ctf);
    // inverse row FFT -> real out
    fft_rows_inv_kernel<<<NIMG * NBOX / 2, 256, 0, stream>>>(freq, out);
}

// Round 22
// 138.416 us; speedup vs baseline: 1.1047x; 1.0125x over previous
//
#include <hip/hip_runtime.h>
#include <hip/hip_bf16.h>

#define NIMG 32
#define NPTS 300000
#define NL   64
#define NBOX 256

#define BANDS  4
#define BROWS  64          // NBOX / BANDS
#define CHUNKS 2
#define CHPTS  (NPTS / CHUNKS)   // 150000

#define WQS  2047.0f             // 11-bit weight quantization scale (16-bit field headroom)
#define WQI  (1.0f / 2047.0f)

typedef float v2f __attribute__((ext_vector_type(2)));
typedef float f32x4 __attribute__((ext_vector_type(4)));
typedef short bf16x8 __attribute__((ext_vector_type(8)));
typedef unsigned long long u64;

__device__ __forceinline__ int rev8(int x) { return (int)(__brev((unsigned)x) >> 24); }

// fp32 -> bf16 round-to-nearest-even
__device__ __forceinline__ short f2bf(float f) {
    unsigned u = __float_as_uint(f);
    unsigned r = (u + 0x7FFFu + ((u >> 16) & 1u)) >> 16;
    return (short)r;
}

// ---------------- zero fill ----------------
__global__ __launch_bounds__(256) void zero_kernel(float4* p, int n4) {
    int i = blockIdx.x * 256 + threadIdx.x;
    if (i < n4) p[i] = make_float4(0.f, 0.f, 0.f, 0.f);
}

// ---------------- P0: per-image fused coefficients + bf16 B matrix ----------------
__global__ __launch_bounds__(256) void uvprep_kernel(
    const float* __restrict__ z_x, const float* __restrict__ z_y,
    const float* __restrict__ z_z, const float* __restrict__ R,
    const float* __restrict__ shifts,
    float4* __restrict__ hdrbuf, short* __restrict__ Bt)
{
    __shared__ float s_u[NIMG * NL];   // 8 KB
    __shared__ float s_v[NIMG * NL];   // 8 KB
    int t = threadIdx.x;
    for (int e = t; e < NIMG * NL; e += 256) {
        int b = e >> 6;
        const float* Rb = R + b * 9;
        float zx = z_x[e], zy = z_y[e], zz = z_z[e];
        s_u[e] = Rb[0] * zx + Rb[1] * zy + Rb[2] * zz;
        s_v[e] = Rb[3] * zx + Rb[4] * zy + Rb[5] * zz;
    }
    if (t < NIMG) {
        const float* Rb = R + t * 9;
        hdrbuf[2 * t]     = make_float4(Rb[0], Rb[1], Rb[2], shifts[2 * t]     + 128.f);
        hdrbuf[2 * t + 1] = make_float4(Rb[3], Rb[4], Rb[5], shifts[2 * t + 1] + 128.f);
    }
    __syncthreads();
    for (int e = t; e < 64 * NL; e += 256) {
        int c = e >> 6, k = e & 63;
        int b = c >> 1;
        float val = (c & 1) ? s_v[b * NL + k] : s_u[b * NL + k];
        Bt[e] = f2bf(val);
    }
}

// ---------------- compact u32 record: pos(16) | fxq(8)<<16 | fyq(8)<<24 ----------------
// fx/fy quantized to 8 bits (== shifting the point by <= 2e-3 px; weight mass exact).
// Edge folds (xi0/yi0 == 255) become fxq/fyq = 0 (algebraically identical).
__device__ __forceinline__ unsigned make_rec32(float px, float py) {
    float x0f = floorf(px), y0f = floorf(py);
    float fx = px - x0f, fy = py - y0f;
    int xi0 = min(max((int)x0f, 0), NBOX - 1);
    int yi0 = min(max((int)y0f, 0), NBOX - 1);
    unsigned fxq = (unsigned)(fx * 255.f + 0.5f); if (fxq > 255u) fxq = 255u;
    unsigned fyq = (unsigned)(fy * 255.f + 0.5f); if (fyq > 255u) fyq = 255u;
    if (xi0 == NBOX - 1) fxq = 0u;   // fold right column left
    if (yi0 == NBOX - 1) fyq = 0u;   // fold bottom row up
    return (unsigned)xi0 | ((unsigned)yi0 << 8) | (fxq << 16) | (fyq << 24);
}

// ---------------- P1: MFMA projection -> one u32 record per (image,point) ----------------
__global__ __launch_bounds__(256) void project_mfma_kernel(
    const float* __restrict__ Zb, const float* __restrict__ coords,
    const float4* __restrict__ hdrbuf, const short* __restrict__ Bt,
    unsigned* __restrict__ recs)
{
    int tid = threadIdx.x;
    int lane = tid & 63;
    int rg = (lane >> 4) & 3;
    bool oddl = (lane & 1);

    bf16x8 bf[4][2];
    #pragma unroll
    for (int t = 0; t < 4; ++t)
        #pragma unroll
        for (int q = 0; q < 2; ++q)
            bf[t][q] = *(const bf16x8*)(Bt + (t * 16 + (lane & 15)) * NL + q * 32 + rg * 8);

    int wid = blockIdx.x * 4 + (tid >> 6);
    int nw  = gridDim.x * 4;
    for (int mt = wid; mt < NPTS / 16; mt += nw) {
        int pbase = mt * 16;
        const float* zrow = Zb + (size_t)(pbase + (lane & 15)) * NL;
        bf16x8 a[2];
        #pragma unroll
        for (int q = 0; q < 2; ++q) {
            float4 f0 = *(const float4*)(zrow + q * 32 + rg * 8);
            float4 f1 = *(const float4*)(zrow + q * 32 + rg * 8 + 4);
            bf16x8 av;
            av[0] = f2bf(f0.x); av[1] = f2bf(f0.y); av[2] = f2bf(f0.z); av[3] = f2bf(f0.w);
            av[4] = f2bf(f1.x); av[5] = f2bf(f1.y); av[6] = f2bf(f1.z); av[7] = f2bf(f1.w);
            a[q] = av;
        }
        f32x4 accs[4];
        #pragma unroll
        for (int t = 0; t < 4; ++t) {
            f32x4 acc = {0.f, 0.f, 0.f, 0.f};
            acc = __builtin_amdgcn_mfma_f32_16x16x32_bf16(a[0], bf[t][0], acc, 0, 0, 0);
            acc = __builtin_amdgcn_mfma_f32_16x16x32_bf16(a[1], bf[t][1], acc, 0, 0, 0);
            accs[t] = acc;
        }

        int ra = rg * 4 + (oddl ? 2 : 0);
        int pa = pbase + ra;
        float cax = coords[3 * pa],     cay = coords[3 * pa + 1], caz = coords[3 * pa + 2];
        float cbx = coords[3 * pa + 3], cby = coords[3 * pa + 4], cbz = coords[3 * pa + 5];

        #pragma unroll
        for (int t = 0; t < 4; ++t) {
            f32x4 acc = accs[t];
            float o0 = __shfl_xor(acc[0], 1, 64);
            float o1 = __shfl_xor(acc[1], 1, 64);
            float o2 = __shfl_xor(acc[2], 1, 64);
            float o3 = __shfl_xor(acc[3], 1, 64);
            float m0 = oddl ? acc[2] : acc[0];
            float m1 = oddl ? acc[3] : acc[1];
            float t0 = oddl ? o2 : o0;
            float t1 = oddl ? o3 : o1;
            float dxa = oddl ? t0 : m0;
            float dya = oddl ? m0 : t0;
            float dxb = oddl ? t1 : m1;
            float dyb = oddl ? m1 : t1;
            int col = t * 16 + (lane & 15);
            int img = col >> 1;
            float4 h0 = hdrbuf[2 * img], h1 = hdrbuf[2 * img + 1];
            float affxa = fmaf(h0.x, cax, fmaf(h0.y, cay, fmaf(h0.z, caz, h0.w)));
            float affya = fmaf(h1.x, cax, fmaf(h1.y, cay, fmaf(h1.z, caz, h1.w)));
            float affxb = fmaf(h0.x, cbx, fmaf(h0.y, cby, fmaf(h0.z, cbz, h0.w)));
            float affyb = fmaf(h1.x, cbx, fmaf(h1.y, cby, fmaf(h1.z, cbz, h1.w)));
            unsigned r0_ = make_rec32(affxa + dxa, affya + dya);
            unsigned r1_ = make_rec32(affxb + dxb, affyb + dyb);
            unsigned* pb = recs + (size_t)img * NPTS;
            *(u64*)(pb + pa) = (u64)r0_ | ((u64)r1_ << 32);   // pa even -> 8B aligned
        }
    }
}

// ---------------- P2: band splat, ONE 2x2-quad u64 atomic per point-image ----------------
// u32 records + weights side-stream (L2-resident); weights reconstructed in-scan.
__global__ __launch_bounds__(1024) void splat2_kernel(
    const unsigned* __restrict__ recs, const float* __restrict__ weights,
    float* __restrict__ img)
{
    __shared__ u64 VA[32 * 128];   // 32 KB
    __shared__ u64 VB[32 * 129];   // 32.25 KB
    __shared__ u64 VC[32 * 128];   // 32 KB
    __shared__ u64 VD[32 * 129];   // 32.25 KB
    int tid = threadIdx.x;
    int id = blockIdx.x;           // band*64 + b*CHUNKS + c  (256 blocks)
    int band = id >> 6;            // 0..3
    int g    = id & 63;
    int b = g >> 1, c = g & 1;

    for (int i = tid; i < 32 * 128; i += 1024) { VA[i] = 0ULL; VC[i] = 0ULL; }
    for (int i = tid; i < 32 * 129; i += 1024) { VB[i] = 0ULL; VD[i] = 0ULL; }
    __syncthreads();

    const int y_lo = band * BROWS;
    const unsigned* rp = recs + (size_t)b * NPTS + (size_t)c * CHPTS;
    const float*    wp = weights + (size_t)c * CHPTS;

    for (int i = 4 * tid; i < CHPTS; i += 4096) {
        uint4  Rv = *(const uint4*)(rp + i);
        float4 Wv = *(const float4*)(wp + i);
        unsigned Ra[4] = {Rv.x, Rv.y, Rv.z, Rv.w};
        float    Wa[4] = {Wv.x, Wv.y, Wv.z, Wv.w};
        #pragma unroll
        for (int k = 0; k < 4; ++k) {
            unsigned rec = Ra[k];
            int xi0 = rec & 255;
            int yi0 = (rec >> 8) & 255;
            int r0 = yi0 - y_lo;
            if ((unsigned)r0 >= BROWS) continue;   // single ownership test
            float w  = Wa[k];
            float fx = (float)((rec >> 16) & 255u) * (1.0f / 255.0f);
            float fy = (float)(rec >> 24) * (1.0f / 255.0f);
            float t1 = w * fy, t0 = w - t1;        // t0 = w*(1-fy)
            float w10 = t0 * fx, w00 = t0 - w10;
            float w11 = t1 * fx, w01 = t1 - w11;
            unsigned q00 = (unsigned)(w00 * WQS + 0.5f);
            unsigned q10 = (unsigned)(w10 * WQS + 0.5f);
            unsigned q01 = (unsigned)(w01 * WQS + 0.5f);
            unsigned q11 = (unsigned)(w11 * WQS + 0.5f);
            u64 val = (u64)q00 | ((u64)q10 << 16) | ((u64)q01 << 32) | ((u64)q11 << 48);
            int qr = r0 >> 1;
            int qc = (xi0 + (xi0 & 1)) >> 1;
            bool xodd = (xi0 & 1), yodd = (r0 & 1);
            u64* base = yodd ? (xodd ? VD : VC) : (xodd ? VB : VA);
            int stride = xodd ? 129 : 128;
            atomicAdd(&base[qr * stride + qc], val);
        }
    }
    __syncthreads();
    int nrows = min(BROWS + 1, NBOX - y_lo);
    float* ib = img + (size_t)b * NBOX * NBOX + (size_t)y_lo * NBOX;
    for (int i = tid; i < nrows * NBOX; i += 1024) {
        int r = i >> 8, x = i & 255;
        int fc0 = x & 1;
        int fc1 = fc0 ^ 1;
        int ja = x >> 1;
        int jb = (x + 1) >> 1;
        unsigned acc = 0;
        if (r < BROWS) {
            int fr = (r & 1) << 1;
            acc += (unsigned)((VA[(r >> 1) * 128 + ja] >> (16 * (fr | fc0))) & 0xFFFFu);
            acc += (unsigned)((VB[(r >> 1) * 129 + jb] >> (16 * (fr | fc1))) & 0xFFFFu);
        }
        if (r >= 1) {
            int fr = ((r & 1) ^ 1) << 1;
            acc += (unsigned)((VC[((r - 1) >> 1) * 128 + ja] >> (16 * (fr | fc0))) & 0xFFFFu);
            acc += (unsigned)((VD[((r - 1) >> 1) * 129 + jb] >> (16 * (fr | fc1))) & 0xFFFFu);
        }
        if (acc) unsafeAtomicAdd(ib + i, (float)acc * WQI);
    }
}

// ---------------- fallback: fused splat with global atomics (small ws) ----------------
__global__ __launch_bounds__(256) void splat_kernel(
    const float* __restrict__ z_x, const float* __restrict__ z_y,
    const float* __restrict__ z_z, const float* __restrict__ Zb,
    const float* __restrict__ coords, const float* __restrict__ weights,
    const float* __restrict__ R, const float* __restrict__ shifts,
    float* __restrict__ img)
{
    __shared__ float s_z[3][NIMG][NL];
    __shared__ float s_R[NIMG][9];
    __shared__ float s_sh[NIMG][2];

    int tid = threadIdx.x;
    for (int i = tid; i < NIMG * NL; i += 256) {
        (&s_z[0][0][0])[i] = z_x[i];
        (&s_z[1][0][0])[i] = z_y[i];
        (&s_z[2][0][0])[i] = z_z[i];
    }
    for (int i = tid; i < NIMG * 9; i += 256) (&s_R[0][0])[i] = R[i];
    if (tid < NIMG * 2) (&s_sh[0][0])[tid] = shifts[tid];
    __syncthreads();

    int p = blockIdx.x * 256 + tid;
    if (p >= NPTS) return;

    float4 zr[16];
    const float4* Zr4 = (const float4*)(Zb + (size_t)p * NL);
    #pragma unroll
    for (int i = 0; i < 16; ++i) zr[i] = Zr4[i];

    float cx0 = coords[3 * p + 0];
    float cy0 = coords[3 * p + 1];
    float cz0 = coords[3 * p + 2];
    float w   = weights[p];

    for (int b = 0; b < NIMG; ++b) {
        const float4* zx4 = (const float4*)s_z[0][b];
        const float4* zy4 = (const float4*)s_z[1][b];
        const float4* zz4 = (const float4*)s_z[2][b];
        float dx = 0.f, dy = 0.f, dz = 0.f;
        #pragma unroll
        for (int i = 0; i < 16; ++i) {
            float4 a = zx4[i];
            dx += a.x * zr[i].x + a.y * zr[i].y + a.z * zr[i].z + a.w * zr[i].w;
            float4 bb = zy4[i];
            dy += bb.x * zr[i].x + bb.y * zr[i].y + bb.z * zr[i].z + bb.w * zr[i].w;
            float4 c = zz4[i];
            dz += c.x * zr[i].x + c.y * zr[i].y + c.z * zr[i].z + c.w * zr[i].w;
        }
        float cx = cx0 + dx, cy = cy0 + dy, cz = cz0 + dz;
        const float* Rb = s_R[b];
        float px = Rb[0] * cx + Rb[1] * cy + Rb[2] * cz + s_sh[b][0] + 128.0f;
        float py = Rb[3] * cx + Rb[4] * cy + Rb[5] * cz + s_sh[b][1] + 128.0f;

        float x0 = floorf(px), y0 = floorf(py);
        float fx = px - x0, fy = py - y0;
        int xi0 = min(max((int)x0, 0), NBOX - 1);
        int yi0 = min(max((int)y0, 0), NBOX - 1);
        int xi1 = min(xi0 + 1, NBOX - 1);
        int yi1 = min(yi0 + 1, NBOX - 1);

        float* ib = img + (size_t)b * NBOX * NBOX;
        unsafeAtomicAdd(ib + yi0 * NBOX + xi0, w * (1.f - fx) * (1.f - fy));
        unsafeAtomicAdd(ib + yi0 * NBOX + xi1, w * fx * (1.f - fy));
        unsafeAtomicAdd(ib + yi1 * NBOX + xi0, w * (1.f - fx) * fy);
        unsafeAtomicAdd(ib + yi1 * NBOX + xi1, w * fx * fy);
    }
}

// ---------------- 256-pt FFT helpers (AOS float2, LDS twiddle) ----------------
__device__ __forceinline__ void fft_dif_t(float2* s, const float2* tw, int t) {
    #pragma unroll
    for (int st = 7; st >= 0; --st) {
        int half = 1 << st;
        int j  = t & (half - 1);
        int i1 = ((t >> st) << (st + 1)) + j;
        int i2 = i1 + half;
        float2 a = s[i1], b = s[i2];
        float2 w = tw[j << (7 - st)];
        float dxr = a.x - b.x, dxi = a.y - b.y;
        s[i1] = make_float2(a.x + b.x, a.y + b.y);
        s[i2] = make_float2(w.x * dxr - w.y * dxi, w.x * dxi + w.y * dxr);
        __syncthreads();
    }
}

__device__ __forceinline__ void fft_dit_t(float2* s, const float2* tw, int t) {
    #pragma unroll
    for (int st = 0; st < 8; ++st) {
        int half = 1 << st;
        int j  = t & (half - 1);
        int i1 = ((t >> st) << (st + 1)) + j;
        int i2 = i1 + half;
        float2 a = s[i1], b = s[i2];
        float2 w = tw[j << (7 - st)];
        float cs = w.x, sn = -w.y;
        float tr = cs * b.x - sn * b.y;
        float ti = cs * b.y + sn * b.x;
        s[i1] = make_float2(a.x + tr, a.y + ti);
        s[i2] = make_float2(a.x - tr, a.y - ti);
        __syncthreads();
    }
}

__device__ __forceinline__ void init_tw(float2* tw, int tid) {
    if (tid < 128) {
        float sn, cs;
        sincosf(-6.283185307179586f * (float)tid * (1.0f / 256.0f), &sn, &cs);
        tw[tid] = make_float2(cs, sn);
    }
}

// ---------------- Pass A: fused 5x5 blur + forward row FFT ----------------
__global__ __launch_bounds__(256) void fft_rows_fwd_blur_kernel(const float* __restrict__ img,
                                                                float2* __restrict__ freq)
{
    __shared__ float2 s[2][NBOX];
    __shared__ float  sb[2][NBOX];
    __shared__ float2 tw[128];
    int tid = threadIdx.x;
    int tx = tid & 127, ty = tid >> 7;
    init_tw(tw, tid);
    int row = blockIdx.x * 2 + ty;     // 0 .. B*N-1
    int b = row >> 8, y = row & (NBOX - 1);
    const float* ib = img + ((size_t)b << 16);
    const float gw[5] = {0.0544886845f, 0.2442013420f, 0.4026199469f,
                         0.2442013420f, 0.0544886845f};
    float acc0 = 0.f, acc1 = 0.f;
    #pragma unroll
    for (int dy = -2; dy <= 2; ++dy) {
        int yy = y + dy;
        if ((unsigned)yy < (unsigned)NBOX) {
            const float* rp = ib + yy * NBOX;
            acc0 += gw[dy + 2] * rp[tx];
            acc1 += gw[dy + 2] * rp[tx + 128];
        }
    }
    sb[ty][tx] = acc0;  sb[ty][tx + 128] = acc1;
    __syncthreads();
    float r0 = 0.f, r1 = 0.f;
    #pragma unroll
    for (int dx = -2; dx <= 2; ++dx) {
        int x0 = tx + dx, x1 = tx + 128 + dx;
        if ((unsigned)x0 < (unsigned)NBOX) r0 += gw[dx + 2] * sb[ty][x0];
        if ((unsigned)x1 < (unsigned)NBOX) r1 += gw[dx + 2] * sb[ty][x1];
    }
    s[ty][tx]       = make_float2(r0, 0.f);
    s[ty][tx + 128] = make_float2(r1, 0.f);
    __syncthreads();
    fft_dif_t(s[ty], tw, tx);
    float2* op = freq + (size_t)row * NBOX;
    op[tx]       = s[ty][tx];
    op[tx + 128] = s[ty][tx + 128];
}

// ---------------- Pass B: 32-column fused fwd-FFT * ctf * inv-FFT (coalesced) ----------------
__global__ __launch_bounds__(1024) void fft_cols_ctf32_kernel(float2* __restrict__ freq,
                                                              const float* __restrict__ ctf)
{
    __shared__ float  s_re[32][257];   // 32.9 KB
    __shared__ float  s_im[32][257];   // 32.9 KB
    __shared__ float2 tw[128];
    int tid = threadIdx.x;
    init_tw(tw, tid);
    int col = tid & 31, tq = tid >> 5;        // tq in 0..31
    int blk = blockIdx.x;
    int b = blk >> 3;
    int x = ((blk & 7) << 5) + col;           // storage x
    float2* base = freq + ((size_t)b << 16) + x;

    #pragma unroll
    for (int k = 0; k < 8; ++k) {
        int j = tq + 32 * k;
        float2 v = base[(size_t)j * NBOX];
        s_re[col][j] = v.x;  s_im[col][j] = v.y;
    }
    __syncthreads();

    #pragma unroll
    for (int st = 7; st >= 0; --st) {
        int half = 1 << st;
        #pragma unroll
        for (int k = 0; k < 4; ++k) {
            int t = tq + 32 * k;
            int jj = t & (half - 1);
            int i1 = ((t >> st) << (st + 1)) + jj;
            int i2 = i1 + half;
            float ar = s_re[col][i1], ai = s_im[col][i1];
            float br = s_re[col][i2], bi = s_im[col][i2];
            float2 w = tw[jj << (7 - st)];
            float dr = ar - br, di = ai - bi;
            s_re[col][i1] = ar + br;  s_im[col][i1] = ai + bi;
            s_re[col][i2] = w.x * dr - w.y * di;
            s_im[col][i2] = w.x * di + w.y * dr;
        }
        __syncthreads();
    }

    const float* cb = ctf + ((size_t)b << 16) + rev8(x);
    #pragma unroll
    for (int k = 0; k < 8; ++k) {
        int j = tq + 32 * k;
        float c = cb[rev8(j) * NBOX];
        s_re[col][j] *= c;  s_im[col][j] *= c;
    }
    __syncthreads();

    #pragma unroll
    for (int st = 0; st < 8; ++st) {
        int half = 1 << st;
        #pragma unroll
        for (int k = 0; k < 4; ++k) {
            int t = tq + 32 * k;
            int jj = t & (half - 1);
            int i1 = ((t >> st) << (st + 1)) + jj;
            int i2 = i1 + half;
            float ar = s_re[col][i1], ai = s_im[col][i1];
            float br = s_re[col][i2], bi = s_im[col][i2];
            float2 w = tw[jj << (7 - st)];
            float cs = w.x, sn = -w.y;
            float tr = cs * br - sn * bi;
            float ti = cs * bi + sn * br;
            s_re[col][i1] = ar + tr;  s_im[col][i1] = ai + ti;
            s_re[col][i2] = ar - tr;  s_im[col][i2] = ai - ti;
        }
        __syncthreads();
    }

    const float inv = 1.0f / 256.0f;
    #pragma unroll
    for (int k = 0; k < 8; ++k) {
        int j = tq + 32 * k;
        base[(size_t)j * NBOX] = make_float2(s_re[col][j] * inv, s_im[col][j] * inv);
    }
}

// ---------------- Pass C: inverse row FFT -> real output ----------------
__global__ __launch_bounds__(256) void fft_rows_inv_kernel(const float2* __restrict__ freq,
                                                           float* __restrict__ out)
{
    __shared__ float2 s[2][NBOX];
    __shared__ float2 tw[128];
    int tid = threadIdx.x;
    int tx = tid & 127, ty = tid >> 7;
    init_tw(tw, tid);
    int row = blockIdx.x * 2 + ty;
    const float2* rp = freq + (size_t)row * NBOX;
    s[ty][tx]       = rp[tx];
    s[ty][tx + 128] = rp[tx + 128];
    __syncthreads();
    fft_dit_t(s[ty], tw, tx);
    const float inv = 1.0f / 256.0f;
    out[(size_t)row * NBOX + tx]       = s[ty][tx].x * inv;
    out[(size_t)row * NBOX + tx + 128] = s[ty][tx + 128].x * inv;
}

extern "C" void kernel_launch(void* const* d_in, const int* in_sizes, int n_in,
                              void* d_out, int out_size, void* d_ws, size_t ws_size,
                              hipStream_t stream)
{
    (void)in_sizes; (void)n_in; (void)out_size;
    const float* z_x     = (const float*)d_in[0];
    const float* z_y     = (const float*)d_in[1];
    const float* z_z     = (const float*)d_in[2];
    const float* Zb      = (const float*)d_in[3];
    const float* coords  = (const float*)d_in[4];
    const float* weights = (const float*)d_in[5];
    const float* R       = (const float*)d_in[6];
    const float* shifts  = (const float*)d_in[7];
    const float* ctf     = (const float*)d_in[8];
    float* out = (float*)d_out;

    const size_t NELEM = (size_t)NIMG * NBOX * NBOX;           // 2,097,152
    char* base = (char*)d_ws;
    float*    img  = (float*)base;                              // 8 MB
    unsigned* recs = (unsigned*)(base + 8388608);               // 38.4 MB
    float4* hdrbuf = (float4*)(base + 8388608 + 38400000);      // 1 KB
    short*  Bt     = (short*)(base + 8388608 + 38400000 + 1024);// 8 KB
    // freq aliases recs (recs dead after splat2; freq written after)
    float2* freq = (float2*)(base + 8388608);                   // 16.78 MB < 38.4 MB
    const size_t required = 8388608 + 38400000 + 1024 + 8192;

    zero_kernel<<<(int)(NELEM / 4 + 255) / 256, 256, 0, stream>>>((float4*)img, (int)(NELEM / 4));

    if (ws_size >= required) {
        uvprep_kernel<<<1, 256, 0, stream>>>(z_x, z_y, z_z, R, shifts, hdrbuf, Bt);
        project_mfma_kernel<<<2048, 256, 0, stream>>>(Zb, coords, hdrbuf, Bt, recs);
        splat2_kernel<<<NIMG * BANDS * CHUNKS, 1024, 0, stream>>>(recs, weights, img);
    } else {
        splat_kernel<<<(NPTS + 255) / 256, 256, 0, stream>>>(z_x, z_y, z_z, Zb, coords,
                                                             weights, R, shifts, img);
    }

    // fused blur + row FFT
    fft_rows_fwd_blur_kernel<<<NIMG * NBOX / 2, 256, 0, stream>>>(img, freq);
    // 32-column fused col-FFT * ctf * inv-col-FFT (coalesced)
    fft_cols_ctf32_kernel<<<NIMG * 8, 1024, 0, stream>>>(freq, ctf);
    // inverse row FFT -> real out
    fft_rows_inv_kernel<<<NIMG * NBOX / 2, 256, 0, stream>>>(freq, out);
}

// Round 24
// 137.747 us; speedup vs baseline: 1.1100x; 1.0049x over previous
//
#include <hip/hip_runtime.h>
#include <hip/hip_bf16.h>

#define NIMG 32
#define NPTS 300000
#define NL   64
#define NBOX 256

#define BANDS  4
#define BROWS  64          // NBOX / BANDS
#define CHUNKS 2
#define CHPTS  (NPTS / CHUNKS)   // 150000

#define WQS  2047.0f             // 11-bit weight quantization scale (16-bit field headroom)
#define WQI  (1.0f / 2047.0f)

typedef float v2f __attribute__((ext_vector_type(2)));
typedef float f32x4 __attribute__((ext_vector_type(4)));
typedef short bf16x8 __attribute__((ext_vector_type(8)));
typedef unsigned long long u64;

__device__ __forceinline__ int rev8(int x) { return (int)(__brev((unsigned)x) >> 24); }

// fp32 -> bf16 round-to-nearest-even
__device__ __forceinline__ short f2bf(float f) {
    unsigned u = __float_as_uint(f);
    unsigned r = (u + 0x7FFFu + ((u >> 16) & 1u)) >> 16;
    return (short)r;
}

// ---------------- zero fill ----------------
__global__ __launch_bounds__(256) void zero_kernel(float4* p, int n4) {
    int i = blockIdx.x * 256 + threadIdx.x;
    if (i < n4) p[i] = make_float4(0.f, 0.f, 0.f, 0.f);
}

// ---------------- P0: per-image fused coefficients + bf16 B matrix ----------------
__global__ __launch_bounds__(256) void uvprep_kernel(
    const float* __restrict__ z_x, const float* __restrict__ z_y,
    const float* __restrict__ z_z, const float* __restrict__ R,
    const float* __restrict__ shifts,
    float4* __restrict__ hdrbuf, short* __restrict__ Bt)
{
    __shared__ float s_u[NIMG * NL];   // 8 KB
    __shared__ float s_v[NIMG * NL];   // 8 KB
    int t = threadIdx.x;
    for (int e = t; e < NIMG * NL; e += 256) {
        int b = e >> 6;
        const float* Rb = R + b * 9;
        float zx = z_x[e], zy = z_y[e], zz = z_z[e];
        s_u[e] = Rb[0] * zx + Rb[1] * zy + Rb[2] * zz;
        s_v[e] = Rb[3] * zx + Rb[4] * zy + Rb[5] * zz;
    }
    if (t < NIMG) {
        const float* Rb = R + t * 9;
        hdrbuf[2 * t]     = make_float4(Rb[0], Rb[1], Rb[2], shifts[2 * t]     + 128.f);
        hdrbuf[2 * t + 1] = make_float4(Rb[3], Rb[4], Rb[5], shifts[2 * t + 1] + 128.f);
    }
    __syncthreads();
    for (int e = t; e < 64 * NL; e += 256) {
        int c = e >> 6, k = e & 63;
        int b = c >> 1;
        float val = (c & 1) ? s_v[b * NL + k] : s_u[b * NL + k];
        Bt[e] = f2bf(val);
    }
}

// ---------------- compact u32 record: pos(16) | fxq(8)<<16 | fyq(8)<<24 ----------------
// fx/fy quantized to 8 bits (== shifting the point by <= 2e-3 px; weight mass exact).
// Edge folds (xi0/yi0 == 255) become fxq/fyq = 0 (algebraically identical).
__device__ __forceinline__ unsigned make_rec32(float px, float py) {
    float x0f = floorf(px), y0f = floorf(py);
    float fx = px - x0f, fy = py - y0f;
    int xi0 = min(max((int)x0f, 0), NBOX - 1);
    int yi0 = min(max((int)y0f, 0), NBOX - 1);
    unsigned fxq = (unsigned)(fx * 255.f + 0.5f); if (fxq > 255u) fxq = 255u;
    unsigned fyq = (unsigned)(fy * 255.f + 0.5f); if (fyq > 255u) fyq = 255u;
    if (xi0 == NBOX - 1) fxq = 0u;   // fold right column left
    if (yi0 == NBOX - 1) fyq = 0u;   // fold bottom row up
    return (unsigned)xi0 | ((unsigned)yi0 << 8) | (fxq << 16) | (fyq << 24);
}

// ---------------- P1: MFMA projection -> one u32 record per (image,point) ----------------
__global__ __launch_bounds__(256) void project_mfma_kernel(
    const float* __restrict__ Zb, const float* __restrict__ coords,
    const float4* __restrict__ hdrbuf, const short* __restrict__ Bt,
    unsigned* __restrict__ recs)
{
    int tid = threadIdx.x;
    int lane = tid & 63;
    int rg = (lane >> 4) & 3;
    bool oddl = (lane & 1);

    bf16x8 bf[4][2];
    #pragma unroll
    for (int t = 0; t < 4; ++t)
        #pragma unroll
        for (int q = 0; q < 2; ++q)
            bf[t][q] = *(const bf16x8*)(Bt + (t * 16 + (lane & 15)) * NL + q * 32 + rg * 8);

    int wid = blockIdx.x * 4 + (tid >> 6);
    int nw  = gridDim.x * 4;
    for (int mt = wid; mt < NPTS / 16; mt += nw) {
        int pbase = mt * 16;
        const float* zrow = Zb + (size_t)(pbase + (lane & 15)) * NL;
        bf16x8 a[2];
        #pragma unroll
        for (int q = 0; q < 2; ++q) {
            float4 f0 = *(const float4*)(zrow + q * 32 + rg * 8);
            float4 f1 = *(const float4*)(zrow + q * 32 + rg * 8 + 4);
            bf16x8 av;
            av[0] = f2bf(f0.x); av[1] = f2bf(f0.y); av[2] = f2bf(f0.z); av[3] = f2bf(f0.w);
            av[4] = f2bf(f1.x); av[5] = f2bf(f1.y); av[6] = f2bf(f1.z); av[7] = f2bf(f1.w);
            a[q] = av;
        }
        f32x4 accs[4];
        #pragma unroll
        for (int t = 0; t < 4; ++t) {
            f32x4 acc = {0.f, 0.f, 0.f, 0.f};
            acc = __builtin_amdgcn_mfma_f32_16x16x32_bf16(a[0], bf[t][0], acc, 0, 0, 0);
            acc = __builtin_amdgcn_mfma_f32_16x16x32_bf16(a[1], bf[t][1], acc, 0, 0, 0);
            accs[t] = acc;
        }

        int ra = rg * 4 + (oddl ? 2 : 0);
        int pa = pbase + ra;
        float cax = coords[3 * pa],     cay = coords[3 * pa + 1], caz = coords[3 * pa + 2];
        float cbx = coords[3 * pa + 3], cby = coords[3 * pa + 4], cbz = coords[3 * pa + 5];

        #pragma unroll
        for (int t = 0; t < 4; ++t) {
            f32x4 acc = accs[t];
            float o0 = __shfl_xor(acc[0], 1, 64);
            float o1 = __shfl_xor(acc[1], 1, 64);
            float o2 = __shfl_xor(acc[2], 1, 64);
            float o3 = __shfl_xor(acc[3], 1, 64);
            float m0 = oddl ? acc[2] : acc[0];
            float m1 = oddl ? acc[3] : acc[1];
            float t0 = oddl ? o2 : o0;
            float t1 = oddl ? o3 : o1;
            float dxa = oddl ? t0 : m0;
            float dya = oddl ? m0 : t0;
            float dxb = oddl ? t1 : m1;
            float dyb = oddl ? m1 : t1;
            int col = t * 16 + (lane & 15);
            int img = col >> 1;
            float4 h0 = hdrbuf[2 * img], h1 = hdrbuf[2 * img + 1];
            float affxa = fmaf(h0.x, cax, fmaf(h0.y, cay, fmaf(h0.z, caz, h0.w)));
            float affya = fmaf(h1.x, cax, fmaf(h1.y, cay, fmaf(h1.z, caz, h1.w)));
            float affxb = fmaf(h0.x, cbx, fmaf(h0.y, cby, fmaf(h0.z, cbz, h0.w)));
            float affyb = fmaf(h1.x, cbx, fmaf(h1.y, cby, fmaf(h1.z, cbz, h1.w)));
            unsigned r0_ = make_rec32(affxa + dxa, affya + dya);
            unsigned r1_ = make_rec32(affxb + dxb, affyb + dyb);
            unsigned* pb = recs + (size_t)img * NPTS;
            *(u64*)(pb + pa) = (u64)r0_ | ((u64)r1_ << 32);   // pa even -> 8B aligned
        }
    }
}

// ---------------- P2: band splat, ONE 2x2-quad u64 atomic per point-image ----------------
// u32 records + weights side-stream (L2-resident); weights reconstructed in-scan.
__global__ __launch_bounds__(1024) void splat2_kernel(
    const unsigned* __restrict__ recs, const float* __restrict__ weights,
    float* __restrict__ img)
{
    __shared__ u64 VA[32 * 128];   // 32 KB
    __shared__ u64 VB[32 * 129];   // 32.25 KB
    __shared__ u64 VC[32 * 128];   // 32 KB
    __shared__ u64 VD[32 * 129];   // 32.25 KB
    int tid = threadIdx.x;
    int id = blockIdx.x;           // band*64 + b*CHUNKS + c  (256 blocks)
    int band = id >> 6;            // 0..3
    int g    = id & 63;
    int b = g >> 1, c = g & 1;

    for (int i = tid; i < 32 * 128; i += 1024) { VA[i] = 0ULL; VC[i] = 0ULL; }
    for (int i = tid; i < 32 * 129; i += 1024) { VB[i] = 0ULL; VD[i] = 0ULL; }
    __syncthreads();

    const int y_lo = band * BROWS;
    const unsigned* rp = recs + (size_t)b * NPTS + (size_t)c * CHPTS;
    const float*    wp = weights + (size_t)c * CHPTS;

    for (int i = 4 * tid; i < CHPTS; i += 4096) {
        uint4  Rv = *(const uint4*)(rp + i);
        float4 Wv = *(const float4*)(wp + i);
        unsigned Ra[4] = {Rv.x, Rv.y, Rv.z, Rv.w};
        float    Wa[4] = {Wv.x, Wv.y, Wv.z, Wv.w};
        #pragma unroll
        for (int k = 0; k < 4; ++k) {
            unsigned rec = Ra[k];
            int xi0 = rec & 255;
            int yi0 = (rec >> 8) & 255;
            int r0 = yi0 - y_lo;
            if ((unsigned)r0 >= BROWS) continue;   // single ownership test
            float w  = Wa[k];
            float fx = (float)((rec >> 16) & 255u) * (1.0f / 255.0f);
            float fy = (float)(rec >> 24) * (1.0f / 255.0f);
            float t1 = w * fy, t0 = w - t1;        // t0 = w*(1-fy)
            float w10 = t0 * fx, w00 = t0 - w10;
            float w11 = t1 * fx, w01 = t1 - w11;
            unsigned q00 = (unsigned)(w00 * WQS + 0.5f);
            unsigned q10 = (unsigned)(w10 * WQS + 0.5f);
            unsigned q01 = (unsigned)(w01 * WQS + 0.5f);
            unsigned q11 = (unsigned)(w11 * WQS + 0.5f);
            u64 val = (u64)q00 | ((u64)q10 << 16) | ((u64)q01 << 32) | ((u64)q11 << 48);
            int qr = r0 >> 1;
            int qc = (xi0 + (xi0 & 1)) >> 1;
            bool xodd = (xi0 & 1), yodd = (r0 & 1);
            u64* base = yodd ? (xodd ? VD : VC) : (xodd ? VB : VA);
            int stride = xodd ? 129 : 128;
            atomicAdd(&base[qr * stride + qc], val);
        }
    }
    __syncthreads();
    int nrows = min(BROWS + 1, NBOX - y_lo);
    float* ib = img + (size_t)b * NBOX * NBOX + (size_t)y_lo * NBOX;
    for (int i = tid; i < nrows * NBOX; i += 1024) {
        int r = i >> 8, x = i & 255;
        int fc0 = x & 1;
        int fc1 = fc0 ^ 1;
        int ja = x >> 1;
        int jb = (x + 1) >> 1;
        unsigned acc = 0;
        if (r < BROWS) {
            int fr = (r & 1) << 1;
            acc += (unsigned)((VA[(r >> 1) * 128 + ja] >> (16 * (fr | fc0))) & 0xFFFFu);
            acc += (unsigned)((VB[(r >> 1) * 129 + jb] >> (16 * (fr | fc1))) & 0xFFFFu);
        }
        if (r >= 1) {
            int fr = ((r & 1) ^ 1) << 1;
            acc += (unsigned)((VC[((r - 1) >> 1) * 128 + ja] >> (16 * (fr | fc0))) & 0xFFFFu);
            acc += (unsigned)((VD[((r - 1) >> 1) * 129 + jb] >> (16 * (fr | fc1))) & 0xFFFFu);
        }
        if (acc) unsafeAtomicAdd(ib + i, (float)acc * WQI);
    }
}

// ---------------- fallback: fused splat with global atomics (small ws) ----------------
__global__ __launch_bounds__(256) void splat_kernel(
    const float* __restrict__ z_x, const float* __restrict__ z_y,
    const float* __restrict__ z_z, const float* __restrict__ Zb,
    const float* __restrict__ coords, const float* __restrict__ weights,
    const float* __restrict__ R, const float* __restrict__ shifts,
    float* __restrict__ img)
{
    __shared__ float s_z[3][NIMG][NL];
    __shared__ float s_R[NIMG][9];
    __shared__ float s_sh[NIMG][2];

    int tid = threadIdx.x;
    for (int i = tid; i < NIMG * NL; i += 256) {
        (&s_z[0][0][0])[i] = z_x[i];
        (&s_z[1][0][0])[i] = z_y[i];
        (&s_z[2][0][0])[i] = z_z[i];
    }
    for (int i = tid; i < NIMG * 9; i += 256) (&s_R[0][0])[i] = R[i];
    if (tid < NIMG * 2) (&s_sh[0][0])[tid] = shifts[tid];
    __syncthreads();

    int p = blockIdx.x * 256 + tid;
    if (p >= NPTS) return;

    float4 zr[16];
    const float4* Zr4 = (const float4*)(Zb + (size_t)p * NL);
    #pragma unroll
    for (int i = 0; i < 16; ++i) zr[i] = Zr4[i];

    float cx0 = coords[3 * p + 0];
    float cy0 = coords[3 * p + 1];
    float cz0 = coords[3 * p + 2];
    float w   = weights[p];

    for (int b = 0; b < NIMG; ++b) {
        const float4* zx4 = (const float4*)s_z[0][b];
        const float4* zy4 = (const float4*)s_z[1][b];
        const float4* zz4 = (const float4*)s_z[2][b];
        float dx = 0.f, dy = 0.f, dz = 0.f;
        #pragma unroll
        for (int i = 0; i < 16; ++i) {
            float4 a = zx4[i];
            dx += a.x * zr[i].x + a.y * zr[i].y + a.z * zr[i].z + a.w * zr[i].w;
            float4 bb = zy4[i];
            dy += bb.x * zr[i].x + bb.y * zr[i].y + bb.z * zr[i].z + bb.w * zr[i].w;
            float4 c = zz4[i];
            dz += c.x * zr[i].x + c.y * zr[i].y + c.z * zr[i].z + c.w * zr[i].w;
        }
        float cx = cx0 + dx, cy = cy0 + dy, cz = cz0 + dz;
        const float* Rb = s_R[b];
        float px = Rb[0] * cx + Rb[1] * cy + Rb[2] * cz + s_sh[b][0] + 128.0f;
        float py = Rb[3] * cx + Rb[4] * cy + Rb[5] * cz + s_sh[b][1] + 128.0f;

        float x0 = floorf(px), y0 = floorf(py);
        float fx = px - x0, fy = py - y0;
        int xi0 = min(max((int)x0, 0), NBOX - 1);
        int yi0 = min(max((int)y0, 0), NBOX - 1);
        int xi1 = min(xi0 + 1, NBOX - 1);
        int yi1 = min(yi0 + 1, NBOX - 1);

        float* ib = img + (size_t)b * NBOX * NBOX;
        unsafeAtomicAdd(ib + yi0 * NBOX + xi0, w * (1.f - fx) * (1.f - fy));
        unsafeAtomicAdd(ib + yi0 * NBOX + xi1, w * fx * (1.f - fy));
        unsafeAtomicAdd(ib + yi1 * NBOX + xi0, w * (1.f - fx) * fy);
        unsafeAtomicAdd(ib + yi1 * NBOX + xi1, w * fx * fy);
    }
}

// ---------------- 256-pt FFT helpers (AOS float2, LDS twiddle) ----------------
__device__ __forceinline__ void fft_dif_t(float2* s, const float2* tw, int t) {
    #pragma unroll
    for (int st = 7; st >= 0; --st) {
        int half = 1 << st;
        int j  = t & (half - 1);
        int i1 = ((t >> st) << (st + 1)) + j;
        int i2 = i1 + half;
        float2 a = s[i1], b = s[i2];
        float2 w = tw[j << (7 - st)];
        float dxr = a.x - b.x, dxi = a.y - b.y;
        s[i1] = make_float2(a.x + b.x, a.y + b.y);
        s[i2] = make_float2(w.x * dxr - w.y * dxi, w.x * dxi + w.y * dxr);
        __syncthreads();
    }
}

__device__ __forceinline__ void fft_dit_t(float2* s, const float2* tw, int t) {
    #pragma unroll
    for (int st = 0; st < 8; ++st) {
        int half = 1 << st;
        int j  = t & (half - 1);
        int i1 = ((t >> st) << (st + 1)) + j;
        int i2 = i1 + half;
        float2 a = s[i1], b = s[i2];
        float2 w = tw[j << (7 - st)];
        float cs = w.x, sn = -w.y;
        float tr = cs * b.x - sn * b.y;
        float ti = cs * b.y + sn * b.x;
        s[i1] = make_float2(a.x + tr, a.y + ti);
        s[i2] = make_float2(a.x - tr, a.y - ti);
        __syncthreads();
    }
}

__device__ __forceinline__ void init_tw(float2* tw, int tid) {
    if (tid < 128) {
        float sn, cs;
        sincosf(-6.283185307179586f * (float)tid * (1.0f / 256.0f), &sn, &cs);
        tw[tid] = make_float2(cs, sn);
    }
}

// ---------------- Pass A: fused 5x5 blur + forward row FFT ----------------
__global__ __launch_bounds__(256) void fft_rows_fwd_blur_kernel(const float* __restrict__ img,
                                                                float2* __restrict__ freq)
{
    __shared__ float2 s[2][NBOX];
    __shared__ float  sb[2][NBOX];
    __shared__ float2 tw[128];
    int tid = threadIdx.x;
    int tx = tid & 127, ty = tid >> 7;
    init_tw(tw, tid);
    int row = blockIdx.x * 2 + ty;     // 0 .. B*N-1
    int b = row >> 8, y = row & (NBOX - 1);
    const float* ib = img + ((size_t)b << 16);
    const float gw[5] = {0.0544886845f, 0.2442013420f, 0.4026199469f,
                         0.2442013420f, 0.0544886845f};
    float acc0 = 0.f, acc1 = 0.f;
    #pragma unroll
    for (int dy = -2; dy <= 2; ++dy) {
        int yy = y + dy;
        if ((unsigned)yy < (unsigned)NBOX) {
            const float* rp = ib + yy * NBOX;
            acc0 += gw[dy + 2] * rp[tx];
            acc1 += gw[dy + 2] * rp[tx + 128];
        }
    }
    sb[ty][tx] = acc0;  sb[ty][tx + 128] = acc1;
    __syncthreads();
    float r0 = 0.f, r1 = 0.f;
    #pragma unroll
    for (int dx = -2; dx <= 2; ++dx) {
        int x0 = tx + dx, x1 = tx + 128 + dx;
        if ((unsigned)x0 < (unsigned)NBOX) r0 += gw[dx + 2] * sb[ty][x0];
        if ((unsigned)x1 < (unsigned)NBOX) r1 += gw[dx + 2] * sb[ty][x1];
    }
    s[ty][tx]       = make_float2(r0, 0.f);
    s[ty][tx + 128] = make_float2(r1, 0.f);
    __syncthreads();
    fft_dif_t(s[ty], tw, tx);
    float2* op = freq + (size_t)row * NBOX;
    op[tx]       = s[ty][tx];
    op[tx + 128] = s[ty][tx + 128];
}

// ---------------- Pass B: 32-column fused fwd-FFT * ctf * inv-FFT (coalesced) ----------------
__global__ __launch_bounds__(1024) void fft_cols_ctf32_kernel(float2* __restrict__ freq,
                                                              const float* __restrict__ ctf)
{
    __shared__ float  s_re[32][257];   // 32.9 KB
    __shared__ float  s_im[32][257];   // 32.9 KB
    __shared__ float2 tw[128];
    int tid = threadIdx.x;
    init_tw(tw, tid);
    int col = tid & 31, tq = tid >> 5;        // tq in 0..31
    int blk = blockIdx.x;
    int b = blk >> 3;
    int x = ((blk & 7) << 5) + col;           // storage x
    float2* base = freq + ((size_t)b << 16) + x;

    #pragma unroll
    for (int k = 0; k < 8; ++k) {
        int j = tq + 32 * k;
        float2 v = base[(size_t)j * NBOX];
        s_re[col][j] = v.x;  s_im[col][j] = v.y;
    }
    __syncthreads();

    #pragma unroll
    for (int st = 7; st >= 0; --st) {
        int half = 1 << st;
        #pragma unroll
        for (int k = 0; k < 4; ++k) {
            int t = tq + 32 * k;
            int jj = t & (half - 1);
            int i1 = ((t >> st) << (st + 1)) + jj;
            int i2 = i1 + half;
            float ar = s_re[col][i1], ai = s_im[col][i1];
            float br = s_re[col][i2], bi = s_im[col][i2];
            float2 w = tw[jj << (7 - st)];
            float dr = ar - br, di = ai - bi;
            s_re[col][i1] = ar + br;  s_im[col][i1] = ai + bi;
            s_re[col][i2] = w.x * dr - w.y * di;
            s_im[col][i2] = w.x * di + w.y * dr;
        }
        __syncthreads();
    }

    const float* cb = ctf + ((size_t)b << 16) + rev8(x);
    #pragma unroll
    for (int k = 0; k < 8; ++k) {
        int j = tq + 32 * k;
        float c = cb[rev8(j) * NBOX];
        s_re[col][j] *= c;  s_im[col][j] *= c;
    }
    __syncthreads();

    #pragma unroll
    for (int st = 0; st < 8; ++st) {
        int half = 1 << st;
        #pragma unroll
        for (int k = 0; k < 4; ++k) {
            int t = tq + 32 * k;
            int jj = t & (half - 1);
            int i1 = ((t >> st) << (st + 1)) + jj;
            int i2 = i1 + half;
            float ar = s_re[col][i1], ai = s_im[col][i1];
            float br = s_re[col][i2], bi = s_im[col][i2];
            float2 w = tw[jj << (7 - st)];
            float cs = w.x, sn = -w.y;
            float tr = cs * br - sn * bi;
            float ti = cs * bi + sn * br;
            s_re[col][i1] = ar + tr;  s_im[col][i1] = ai + ti;
            s_re[col][i2] = ar - tr;  s_im[col][i2] = ai - ti;
        }
        __syncthreads();
    }

    const float inv = 1.0f / 256.0f;
    #pragma unroll
    for (int k = 0; k < 8; ++k) {
        int j = tq + 32 * k;
        base[(size_t)j * NBOX] = make_float2(s_re[col][j] * inv, s_im[col][j] * inv);
    }
}

// ---------------- Pass C: inverse row FFT -> real output ----------------
__global__ __launch_bounds__(256) void fft_rows_inv_kernel(const float2* __restrict__ freq,
                                                           float* __restrict__ out)
{
    __shared__ float2 s[2][NBOX];
    __shared__ float2 tw[128];
    int tid = threadIdx.x;
    int tx = tid & 127, ty = tid >> 7;
    init_tw(tw, tid);
    int row = blockIdx.x * 2 + ty;
    const float2* rp = freq + (size_t)row * NBOX;
    s[ty][tx]       = rp[tx];
    s[ty][tx + 128] = rp[tx + 128];
    __syncthreads();
    fft_dit_t(s[ty], tw, tx);
    const float inv = 1.0f / 256.0f;
    out[(size_t)row * NBOX + tx]       = s[ty][tx].x * inv;
    out[(size_t)row * NBOX + tx + 128] = s[ty][tx + 128].x * inv;
}

extern "C" void kernel_launch(void* const* d_in, const int* in_sizes, int n_in,
                              void* d_out, int out_size, void* d_ws, size_t ws_size,
                              hipStream_t stream)
{
    (void)in_sizes; (void)n_in; (void)out_size;
    const float* z_x     = (const float*)d_in[0];
    const float* z_y     = (const float*)d_in[1];
    const float* z_z     = (const float*)d_in[2];
    const float* Zb      = (const float*)d_in[3];
    const float* coords  = (const float*)d_in[4];
    const float* weights = (const float*)d_in[5];
    const float* R       = (const float*)d_in[6];
    const float* shifts  = (const float*)d_in[7];
    const float* ctf     = (const float*)d_in[8];
    float* out = (float*)d_out;

    const size_t NELEM = (size_t)NIMG * NBOX * NBOX;           // 2,097,152
    char* base = (char*)d_ws;
    float*    img  = (float*)base;                              // 8 MB
    unsigned* recs = (unsigned*)(base + 8388608);               // 38.4 MB
    float4* hdrbuf = (float4*)(base + 8388608 + 38400000);      // 1 KB
    short*  Bt     = (short*)(base + 8388608 + 38400000 + 1024);// 8 KB
    // freq aliases recs (recs dead after splat2; freq written after)
    float2* freq = (float2*)(base + 8388608);                   // 16.78 MB < 38.4 MB
    const size_t required = 8388608 + 38400000 + 1024 + 8192;

    zero_kernel<<<(int)(NELEM / 4 + 255) / 256, 256, 0, stream>>>((float4*)img, (int)(NELEM / 4));

    if (ws_size >= required) {
        uvprep_kernel<<<1, 256, 0, stream>>>(z_x, z_y, z_z, R, shifts, hdrbuf, Bt);
        project_mfma_kernel<<<2048, 256, 0, stream>>>(Zb, coords, hdrbuf, Bt, recs);
        splat2_kernel<<<NIMG * BANDS * CHUNKS, 1024, 0, stream>>>(recs, weights, img);
    } else {
        splat_kernel<<<(NPTS + 255) / 256, 256, 0, stream>>>(z_x, z_y, z_z, Zb, coords,
                                                             weights, R, shifts, img);
    }

    // fused blur + row FFT
    fft_rows_fwd_blur_kernel<<<NIMG * NBOX / 2, 256, 0, stream>>>(img, freq);
    // 32-column fused col-FFT * ctf * inv-col-FFT (coalesced)
    fft_cols_ctf32_kernel<<<NIMG * 8, 1024, 0, stream>>>(freq, ctf);
    // inverse row FFT -> real out
    fft_rows_inv_kernel<<<NIMG * NBOX / 2, 256, 0, stream>>>(freq, out);
}